// Round 17
// baseline (250.641 us; speedup 1.0000x reference)
//
#include <hip/hip_runtime.h>
#include <hip/hip_bf16.h>
#include <math.h>

#define G_CNT 4
#define U_CNT 100000
#define I_CNT 50000
#define N_ROWS (U_CNT + I_CNT)
#define D_DIM 64
#define T_STEPS 4
#define L_SEQ 50
#define B_CNT 2048
#define NPRED 8192
#define NS_CNT 4096
#define LEAKY_A 0.5f

typedef short bf16x8 __attribute__((ext_vector_type(8)));
typedef float f32x4 __attribute__((ext_vector_type(4)));

union U16B { unsigned u[4]; bf16x8 v; };

// f32 -> bf16 RNE, pure C (no inline asm)
__device__ __forceinline__ unsigned bfr(float x) {
    unsigned u = __float_as_uint(x);
    return (u + 0x7fffu + ((u >> 16) & 1u)) >> 16;
}
__device__ __forceinline__ unsigned pkbf(float a, float b) {
    return bfr(a) | (bfr(b) << 16);
}
__device__ __forceinline__ float bf_lo(unsigned u) { return __uint_as_float(u << 16); }
__device__ __forceinline__ float bf_hi(unsigned u) { return __uint_as_float(u & 0xffff0000u); }

__device__ __forceinline__ float bcast(float v, int srcLane) {
    return __int_as_float(__builtin_amdgcn_readlane(__float_as_int(v), srcLane));
}

__device__ __forceinline__ float waveReduceSum(float v) {
    v += __shfl_xor(v, 1, 64);
    v += __shfl_xor(v, 2, 64);
    v += __shfl_xor(v, 4, 64);
    v += __shfl_xor(v, 8, 64);
    v += __shfl_xor(v, 16, 64);
    v += __shfl_xor(v, 32, 64);
    return v;
}

__device__ __forceinline__ float waveLayerNorm(float v) {
    float s  = waveReduceSum(v);
    float s2 = waveReduceSum(v * v);
    float mean = s * (1.0f / 64.0f);
    float var  = s2 * (1.0f / 64.0f) - mean * mean;
    return (v - mean) * rsqrtf(var + 1e-5f);
}

// r12 lesson: every f32 divide (no -ffast-math) = ~10-12 VALU instr.
__device__ __forceinline__ float rcp_(float x) { return __builtin_amdgcn_rcpf(x); }

__device__ __forceinline__ float sigm(float x) { return rcp_(1.0f + __expf(-x)); }
__device__ __forceinline__ float tanh_(float x) {
    float xc = fminf(x, 15.0f);
    float t = __expf(2.0f * xc);
    return (t - 1.0f) * rcp_(t + 1.0f);
}
__device__ __forceinline__ float leakyf(float x) { return x >= 0.0f ? x : LEAKY_A * x; }

// Gate-row permutation: lane (r,g)'s output dims == its own B-frag k-slots
// -> h/xn feed the next MFMA B operand as pure register reuse.
__device__ __forceinline__ int gate_perm(int m, int p) {
    int ty = m >> 2, mm = m & 3;
    return ty * 64 + 32 * (mm >> 1) + 8 * (p >> 2) + 4 * (mm & 1) + (p & 3);
}

// ---------------------------------------------------------------------------
// prep_kernel: one-shot pack of weight fragments into d_ws.
// Wih scaled by 3.0 (gates = (3Wih)@emb == Wih@(3emb)).
// ---------------------------------------------------------------------------
__global__ __launch_bounds__(512)
void prep_kernel(const float* __restrict__ Wih, const float* __restrict__ Whh,
                 const float* __restrict__ bih, const float* __restrict__ bhh,
                 const float* __restrict__ Wq0, const float* __restrict__ Wk0, const float* __restrict__ Wv0,
                 const float* __restrict__ Wq1, const float* __restrict__ Wk1, const float* __restrict__ Wv1,
                 char* __restrict__ fragtab, float* __restrict__ biastab)
{
    const int tid  = threadIdx.x;
    const int lane = tid & 63;
    const int wave = tid >> 6;
    const int r    = lane & 15;
    const int g    = lane >> 4;

#pragma unroll
    for (int i = 0; i < 8; ++i) {
        int f = wave * 8 + i;               // 0..63
        int m = f >> 2, kc = f & 3;
        int gate = gate_perm(m, r);
        int k0 = kc * 32 + 8 * g;
        const bool isX = (k0 < 64);
        const float sc = isX ? 3.0f : 1.0f;           // fold x3 into Wih
        const float* src = isX ? (Wih + gate * 64 + k0)
                               : (Whh + gate * 64 + (k0 - 64));
        float4 lo = *(const float4*)src;
        float4 hi = *(const float4*)(src + 4);
        U16B u;
        u.u[0] = pkbf(sc * lo.x, sc * lo.y); u.u[1] = pkbf(sc * lo.z, sc * lo.w);
        u.u[2] = pkbf(sc * hi.x, sc * hi.y); u.u[3] = pkbf(sc * hi.z, sc * hi.w);
        *(bf16x8*)(fragtab + f * 1024 + lane * 16) = u.v;
    }
#pragma unroll
    for (int i = 0; i < 6; ++i) {
        int f = 64 + i * 8 + wave;              // slot = wave = m*2+kc
        int m = (wave >> 1) & 3, kc = wave & 1;
        const float* WM = (i == 0) ? Wq0 : (i == 1) ? Wk0 : (i == 2) ? Wv0
                        : (i == 3) ? Wq1 : (i == 4) ? Wk1 : Wv1;
        int dp = m * 16 + r;
        int k0 = kc * 32 + 8 * g;
        float v0 = WM[(k0 + 0) * 64 + dp], v1 = WM[(k0 + 1) * 64 + dp];
        float v2 = WM[(k0 + 2) * 64 + dp], v3 = WM[(k0 + 3) * 64 + dp];
        float v4 = WM[(k0 + 4) * 64 + dp], v5 = WM[(k0 + 5) * 64 + dp];
        float v6 = WM[(k0 + 6) * 64 + dp], v7 = WM[(k0 + 7) * 64 + dp];
        U16B u;
        u.u[0] = pkbf(v0, v1); u.u[1] = pkbf(v2, v3);
        u.u[2] = pkbf(v4, v5); u.u[3] = pkbf(v6, v7);
        *(bf16x8*)(fragtab + f * 1024 + lane * 16) = u.v;
    }
    if (tid < 256) {
        int m = tid >> 4, p = tid & 15;
        int gate = gate_perm(m, p);
        biastab[tid] = bih[gate] + bhh[gate];
    }
}

// ---------------------------------------------------------------------------
// MFMA tower, templated on side (user/item) so the block's 24KB of QKV frags
// can be staged in LDS (base3 block-uniform). r15 left two exposed-latency
// sites: (a) x-embed HBM loads at each t head (~900cyc x4) -> software
// prefetch of t+1 raw float4s during t's compute; (b) QKV fragtab L2 reads
// re-exposed at each head pin -> QFRAG LDS stage. LDS 153KB (still 1
// block/CU -- occupancy pinned structurally since r9, LDS is free).
// ---------------------------------------------------------------------------
template <bool IS_USER>
__global__ __launch_bounds__(512)
void tower_kernel(const float* __restrict__ embAll,
                  const char* __restrict__ fragtab, const float* __restrict__ biastab,
                  float* __restrict__ finalv)
{
    __shared__ char WFRAG[65536];   // LSTM frags 0..63
    __shared__ char QFRAG[24576];   // this side's 24 QKV frags (q,k,v x 8 slots)
    __shared__ char XNF[65536];     // per-wave 8KB: xnf[t][c][lane] bf16x8
    __shared__ float BSL[256];

    const int tid  = threadIdx.x;
    const int lane = tid & 63;
    const int wave = tid >> 6;
    const int r    = lane & 15;
    const int g    = lane >> 4;

    constexpr int SIDE_ROWS = IS_USER ? U_CNT : I_CNT;
    constexpr int BASE3     = IS_USER ? 0 : 3;

    // ---- stage LSTM + QKV frags + bias into LDS (coalesced 16B/lane) ----
#pragma unroll
    for (int i = 0; i < 8; ++i) {
        int off = (wave * 8 + i) * 1024 + lane * 16;
        *(bf16x8*)(WFRAG + off) = *(const bf16x8*)(fragtab + off);
    }
#pragma unroll
    for (int i = 0; i < 3; ++i) {
        int off = (wave * 3 + i) * 1024 + lane * 16;   // 24 frags, contiguous
        *(bf16x8*)(QFRAG + off) =
            *(const bf16x8*)(fragtab + (size_t)(64 + BASE3 * 8) * 1024 + off);
    }
    if (tid < 256) BSL[tid] = biastab[tid];
    __syncthreads();

    const int rowBase0 = blockIdx.x * 128 + wave * 16;
    const bool active  = rowBase0 < SIDE_ROWS;         // wave-uniform (16 | rows)
    const int rowBase  = active ? rowBase0 : (SIDE_ROWS - 16);
    const int rloc     = rowBase + r;

    char* xnfw = XNF + wave * 8192;     // wave-private xnf stage

    float cst[4][4];
#pragma unroll
    for (int mm = 0; mm < 4; ++mm)
#pragma unroll
        for (int rg = 0; rg < 4; ++rg) cst[mm][rg] = 0.0f;

    uint2 hp4[4];                   // packed h of current step (perm'd dims)

    // ---- prefetch raw x for t=0 ----
    float4 rlo[2], rhi[2];
#pragma unroll
    for (int c = 0; c < 2; ++c) {
        const float* p = embAll + (size_t)rloc * 64 + c * 32 + 8 * g;
        rlo[c] = *(const float4*)p;
        rhi[c] = *(const float4*)(p + 4);
    }

#pragma unroll
    for (int t = 0; t < 4; ++t) {
        // ---- pack this step's x B-frags from the prefetched raws ----
        bf16x8 xft[2];
#pragma unroll
        for (int c = 0; c < 2; ++c) {
            U16B u;
            u.u[0] = pkbf(rlo[c].x, rlo[c].y);
            u.u[1] = pkbf(rlo[c].z, rlo[c].w);
            u.u[2] = pkbf(rhi[c].x, rhi[c].y);
            u.u[3] = pkbf(rhi[c].z, rhi[c].w);
            xft[c] = u.v;
        }
        // ---- issue t+1's raw loads now; they fly under this t's compute ----
        if (t < 3) {
#pragma unroll
            for (int c = 0; c < 2; ++c) {
                const float* p = embAll + ((size_t)(t + 1) * SIDE_ROWS + rloc) * 64 + c * 32 + 8 * g;
                rlo[c] = *(const float4*)p;
                rhi[c] = *(const float4*)(p + 4);
            }
        }
        // ---- h B-frags: pure register reuse (gate_perm) ----
        bf16x8 hfr[2];
        if (t > 0) {
#pragma unroll
            for (int c = 0; c < 2; ++c) {
                U16B u;
                u.u[0] = hp4[2 * c].x;     u.u[1] = hp4[2 * c].y;
                u.u[2] = hp4[2 * c + 1].x; u.u[3] = hp4[2 * c + 1].y;
                hfr[c] = u.v;
            }
        }
        __builtin_amdgcn_sched_barrier(0);       // B-frags settled

        // ---- per-mm gate groups: only 4 f32x4 accumulators live at once ----
#pragma unroll
        for (int mm = 0; mm < 4; ++mm) {
            f32x4 acc[4];               // ty = i,f,g,o ; gate tile m = ty*4+mm
#pragma unroll
            for (int ty = 0; ty < 4; ++ty)
                acc[ty] = *(const f32x4*)((const char*)BSL + (ty * 4 + mm) * 64 + g * 16);
#pragma unroll
            for (int kc = 0; kc < 2; ++kc)
#pragma unroll
                for (int ty = 0; ty < 4; ++ty) {
                    bf16x8 af = *(const bf16x8*)(WFRAG + ((ty * 4 + mm) * 4 + kc) * 1024 + lane * 16);
                    acc[ty] = __builtin_amdgcn_mfma_f32_16x16x32_bf16(af, xft[kc], acc[ty], 0, 0, 0);
                }
            if (t > 0) {
#pragma unroll
                for (int c = 0; c < 2; ++c)
#pragma unroll
                    for (int ty = 0; ty < 4; ++ty) {
                        bf16x8 af = *(const bf16x8*)(WFRAG + ((ty * 4 + mm) * 4 + 2 + c) * 1024 + lane * 16);
                        acc[ty] = __builtin_amdgcn_mfma_f32_16x16x32_bf16(af, hfr[c], acc[ty], 0, 0, 0);
                    }
            }
            float hv[4];
#pragma unroll
            for (int rg = 0; rg < 4; ++rg) {
                float cc = sigm(acc[1][rg]) * cst[mm][rg] + sigm(acc[0][rg]) * tanh_(acc[2][rg]);
                cst[mm][rg] = cc;
                hv[rg] = sigm(acc[3][rg]) * tanh_(cc);
            }
            hp4[mm].x = pkbf(hv[0], hv[1]);
            hp4[mm].y = pkbf(hv[2], hv[3]);
            __builtin_amdgcn_sched_barrier(0);   // pin mm-group boundary
        }

        // ---- inline LayerNorm; xn frags go straight to LDS (lane-local) ----
        {
            float hv[16];
#pragma unroll
            for (int mm = 0; mm < 4; ++mm) {
                hv[mm * 4 + 0] = bf_lo(hp4[mm].x); hv[mm * 4 + 1] = bf_hi(hp4[mm].x);
                hv[mm * 4 + 2] = bf_lo(hp4[mm].y); hv[mm * 4 + 3] = bf_hi(hp4[mm].y);
            }
            float s = 0.f, s2 = 0.f;
#pragma unroll
            for (int i2 = 0; i2 < 16; ++i2) { s += hv[i2]; s2 += hv[i2] * hv[i2]; }
            s  += __shfl_xor(s, 16, 64);  s  += __shfl_xor(s, 32, 64);
            s2 += __shfl_xor(s2, 16, 64); s2 += __shfl_xor(s2, 32, 64);
            float mean = s * (1.f / 64.f);
            float var  = s2 * (1.f / 64.f) - mean * mean;
            float rs = rsqrtf(var + 1e-5f);
            uint2 xp[4];
#pragma unroll
            for (int mm = 0; mm < 4; ++mm) {
                float x0 = (hv[mm * 4 + 0] - mean) * rs, x1 = (hv[mm * 4 + 1] - mean) * rs;
                float x2 = (hv[mm * 4 + 2] - mean) * rs, x3 = (hv[mm * 4 + 3] - mean) * rs;
                xp[mm].x = pkbf(x0, x1); xp[mm].y = pkbf(x2, x3);
            }
#pragma unroll
            for (int c = 0; c < 2; ++c) {
                U16B u;
                u.u[0] = xp[2 * c].x;     u.u[1] = xp[2 * c].y;
                u.u[2] = xp[2 * c + 1].x; u.u[3] = xp[2 * c + 1].y;
                *(bf16x8*)(xnfw + t * 2048 + c * 1024 + lane * 16) = u.v;
            }
        }
        __builtin_amdgcn_sched_barrier(0);       // pin t-iteration boundary
    }

    // ---- per-head QKV + attention; frags hoisted per mm from LDS ----
    float* dst = finalv + (size_t)((IS_USER ? 0 : U_CNT) + rowBase + r) * 64;

#pragma unroll
    for (int mm = 0; mm < 4; ++mm) {
        bf16x8 fq[2], fk[2], fv[2];
#pragma unroll
        for (int kc = 0; kc < 2; ++kc) {
            fq[kc] = *(const bf16x8*)(QFRAG + (0 * 8 + mm * 2 + kc) * 1024 + lane * 16);
            fk[kc] = *(const bf16x8*)(QFRAG + (1 * 8 + mm * 2 + kc) * 1024 + lane * 16);
            fv[kc] = *(const bf16x8*)(QFRAG + (2 * 8 + mm * 2 + kc) * 1024 + lane * 16);
        }
        float q[4][4], k[4][4], v[4][4];
#pragma unroll
        for (int t = 0; t < 4; ++t) {
            f32x4 aq = {0.f, 0.f, 0.f, 0.f};
            f32x4 ak = {0.f, 0.f, 0.f, 0.f};
            f32x4 av = {0.f, 0.f, 0.f, 0.f};
#pragma unroll
            for (int kc = 0; kc < 2; ++kc) {
                bf16x8 xn = *(const bf16x8*)(xnfw + t * 2048 + kc * 1024 + lane * 16);
                aq = __builtin_amdgcn_mfma_f32_16x16x32_bf16(fq[kc], xn, aq, 0, 0, 0);
                ak = __builtin_amdgcn_mfma_f32_16x16x32_bf16(fk[kc], xn, ak, 0, 0, 0);
                av = __builtin_amdgcn_mfma_f32_16x16x32_bf16(fv[kc], xn, av, 0, 0, 0);
            }
#pragma unroll
            for (int rg = 0; rg < 4; ++rg) {
                q[t][rg] = aq[rg]; k[t][rg] = ak[rg]; v[t][rg] = av[rg];
            }
            __builtin_amdgcn_sched_barrier(0);   // pin QKV t-iter
        }
        float sc[4][4];                 // [t][s]
#pragma unroll
        for (int t = 0; t < 4; ++t)
#pragma unroll
            for (int s5 = 0; s5 < 4; ++s5) {
                float pr = q[t][0] * k[s5][0] + q[t][1] * k[s5][1]
                         + q[t][2] * k[s5][2] + q[t][3] * k[s5][3];
                pr += __shfl_xor(pr, 16, 64);
                pr += __shfl_xor(pr, 32, 64);
                sc[t][s5] = pr * 0.25f;
            }
        float o0 = 0.f, o1 = 0.f, o2 = 0.f, o3 = 0.f;
#pragma unroll
        for (int t = 0; t < 4; ++t) {
            float mx = fmaxf(fmaxf(sc[t][0], sc[t][1]), fmaxf(sc[t][2], sc[t][3]));
            float e0 = __expf(sc[t][0] - mx), e1 = __expf(sc[t][1] - mx);
            float e2 = __expf(sc[t][2] - mx), e3 = __expf(sc[t][3] - mx);
            float inv = rcp_(e0 + e1 + e2 + e3);
            float a0 = e0 * inv, a1 = e1 * inv, a2 = e2 * inv, a3 = e3 * inv;
            o0 += a0 * v[0][0] + a1 * v[1][0] + a2 * v[2][0] + a3 * v[3][0];
            o1 += a0 * v[0][1] + a1 * v[1][1] + a2 * v[2][1] + a3 * v[3][1];
            o2 += a0 * v[0][2] + a1 * v[1][2] + a2 * v[2][2] + a3 * v[3][2];
            o3 += a0 * v[0][3] + a1 * v[1][3] + a2 * v[2][3] + a3 * v[3][3];
        }
        if (active) {
            float4 o4 = { o0 * 0.25f, o1 * 0.25f, o2 * 0.25f, o3 * 0.25f };
            *(float4*)(dst + mm * 16 + 4 * g) = o4;
        }
        __builtin_amdgcn_sched_barrier(0);   // pin head boundary
    }
}

// ---------------------------------------------------------------------------
// Sequence aggregation + 2 degenerate (T=1) attention layers -> att_user (B,64)
// ---------------------------------------------------------------------------
__global__ __launch_bounds__(256)
void seq_att_kernel(const float* __restrict__ finalv, const float* __restrict__ posEmbed,
                    const float* __restrict__ mask, const int* __restrict__ sequence,
                    const float* __restrict__ Wv_seq, float* __restrict__ att_user)
{
    const int lane = threadIdx.x & 63, wave = threadIdx.x >> 6;
    const int b = blockIdx.x * 4 + wave;
    if (b >= B_CNT) return;
    const float* fitem = finalv + (size_t)U_CNT * D_DIM;

    float acc = 0.0f;
    for (int l = 0; l < L_SEQ; ++l) {
        int   sid = sequence[b * L_SEQ + l];
        float m   = mask[b * L_SEQ + l];
        acc += m * (fitem[(size_t)sid * D_DIM + lane] + posEmbed[l * D_DIM + lane]);
    }
    float att = waveLayerNorm(acc);   // sb
#pragma unroll
    for (int layer = 0; layer < 2; ++layer) {
        float xnv = waveLayerNorm(att);
        float vv = 0.0f;
        const float* Wv = Wv_seq + layer * 64 * 64;
        for (int j = 0; j < 64; ++j)
            vv = fmaf(bcast(xnv, j), Wv[j * 64 + lane], vv);
        att = leakyf(vv) + att;
    }
    att_user[b * D_DIM + lane] = att;
}

// ---------------------------------------------------------------------------
// preds[n] = <fu[uids], fi[iids]> + <leaky(att_user[uLocs]), fi[iids]>
// ---------------------------------------------------------------------------
__global__ __launch_bounds__(256)
void preds_kernel(const float* __restrict__ finalv, const float* __restrict__ att_user,
                  const int* __restrict__ uids, const int* __restrict__ iids,
                  const int* __restrict__ uLocs, float* __restrict__ out)
{
    const int lane = threadIdx.x & 63, wave = threadIdx.x >> 6;
    const int n = blockIdx.x * 4 + wave;
    if (n >= NPRED) return;
    const int u = uids[n], it = iids[n], loc = uLocs[n];
    float fi = finalv[(size_t)(U_CNT + it) * D_DIM + lane];
    float fu = finalv[(size_t)u * D_DIM + lane];
    float au = leakyf(att_user[loc * D_DIM + lane]);
    float p = waveReduceSum(fu * fi + au * fi);
    if (lane == 0) out[n] = p;
}

// ---------------------------------------------------------------------------
// Per (g,s) sample: user_weight (meta MLP), S_final, p1
// ---------------------------------------------------------------------------
__global__ __launch_bounds__(256)
void pergs_kernel(const float* __restrict__ finalv,
                  const float* __restrict__ uEmbed, const float* __restrict__ iEmbed,
                  const int* __restrict__ suids, const int* __restrict__ siids,
                  const float* __restrict__ W2, const float* __restrict__ b2,
                  const float* __restrict__ W3, const float* __restrict__ b3,
                  float* __restrict__ uw, float* __restrict__ SfB, float* __restrict__ p1B)
{
    const int lane = threadIdx.x & 63, wave = threadIdx.x >> 6;
    const int idx = blockIdx.x * 4 + wave;        // 0 .. G*NS-1
    if (idx >= G_CNT * NS_CNT) return;
    const int g  = idx >> 12;                     // NS_CNT == 4096
    const int su = suids[idx], si = siids[idx];

    float fu = finalv[(size_t)su * D_DIM + lane];
    float fi = finalv[(size_t)(U_CNT + si) * D_DIM + lane];
    float uv = 3.0f * uEmbed[((size_t)g * U_CNT + su) * D_DIM + lane];
    float iv = 3.0f * iEmbed[((size_t)g * I_CNT + si) * D_DIM + lane];

    float sf = waveReduceSum(leakyf(fu * fi));
    float pp = waveReduceSum(leakyf(uv * iv));

    float m1a = fu * uv;
    float acc3 = 0.0f;
    for (int o = 0; o < 32; ++o) {
        float part = m1a * W2[o * 192 + lane]
                   + fu  * W2[o * 192 + 64 + lane]
                   + uv  * W2[o * 192 + 128 + lane];
        part = waveReduceSum(part);
        float m2 = leakyf(part + b2[o]);
        acc3 = fmaf(m2, W3[o], acc3);
    }
    float w = rcp_(1.0f + __expf(-(acc3 + b3[0])));
    if (lane == 0) { uw[idx] = w; SfB[idx] = sf; p1B[idx] = pp; }
}

// ---------------------------------------------------------------------------
// Final hinge loss, single block (deterministic)
// ---------------------------------------------------------------------------
__global__ __launch_bounds__(1024)
void ssl_kernel(const float* __restrict__ uw, const float* __restrict__ SfB,
                const float* __restrict__ p1B, float* __restrict__ out)
{
    const int tid = threadIdx.x;
    float local = 0.0f;
    for (int p = tid; p < G_CNT * 2048; p += 1024) {
        int g = p >> 11, s = p & 2047;
        int ip = g * NS_CNT + s, in_ = ip + 2048;
        float Sf   = uw[ip] * SfB[ip] - uw[in_] * SfB[in_];
        float diff = p1B[ip] - p1B[in_];
        local += fmaxf(1.0f - Sf * diff, 0.0f);
    }
    local = waveReduceSum(local);
    __shared__ float part[16];
    const int wave = tid >> 6, lane = tid & 63;
    if (lane == 0) part[wave] = local;
    __syncthreads();
    if (tid == 0) {
        float s = 0.0f;
        for (int i = 0; i < 16; ++i) s += part[i];
        out[NPRED] = s;
    }
}

extern "C" void kernel_launch(void* const* d_in, const int* in_sizes, int n_in,
                              void* d_out, int out_size, void* d_ws, size_t ws_size,
                              hipStream_t stream)
{
    const float* uEmbed  = (const float*)d_in[0];
    const float* iEmbed  = (const float*)d_in[1];
    const float* posEmbed= (const float*)d_in[2];
    const float* Wih     = (const float*)d_in[3];
    const float* Whh     = (const float*)d_in[4];
    const float* bih     = (const float*)d_in[5];
    const float* bhh     = (const float*)d_in[6];
    const float* Wq0     = (const float*)d_in[7];
    const float* Wk0     = (const float*)d_in[8];
    const float* Wv0     = (const float*)d_in[9];
    const float* Wq1     = (const float*)d_in[10];
    const float* Wk1     = (const float*)d_in[11];
    const float* Wv1     = (const float*)d_in[12];
    const float* Wv_seq  = (const float*)d_in[15];
    const float* meta2_W = (const float*)d_in[16];
    const float* meta2_b = (const float*)d_in[17];
    const float* meta3_W = (const float*)d_in[18];
    const float* meta3_b = (const float*)d_in[19];
    const float* mask    = (const float*)d_in[20];
    const int*   uids    = (const int*)d_in[21];
    const int*   iids    = (const int*)d_in[22];
    const int*   sequence= (const int*)d_in[23];
    const int*   uLocs   = (const int*)d_in[24];
    const int*   suids   = (const int*)d_in[25];
    const int*   siids   = (const int*)d_in[26];

    char*  wsB      = (char*)d_ws;
    char*  fragtab  = wsB;                                 // 112KB frags
    float* biastab  = (float*)(wsB + 116 * 1024);          // 1KB bias
    float* finalv   = (float*)(wsB + 128 * 1024);          // N_ROWS*64
    float* att_user = finalv + (size_t)N_ROWS * D_DIM;     // B*64
    float* uwB      = att_user + (size_t)B_CNT * D_DIM;    // G*NS
    float* SfB      = uwB + (size_t)G_CNT * NS_CNT;
    float* p1B      = SfB + (size_t)G_CNT * NS_CNT;
    float* out      = (float*)d_out;

    prep_kernel<<<1, 512, 0, stream>>>(
        Wih, Whh, bih, bhh, Wq0, Wk0, Wv0, Wq1, Wk1, Wv1, fragtab, biastab);

    tower_kernel<true><<<(U_CNT + 127) / 128, 512, 0, stream>>>(
        uEmbed, fragtab, biastab, finalv);
    tower_kernel<false><<<(I_CNT + 127) / 128, 512, 0, stream>>>(
        iEmbed, fragtab, biastab, finalv);

    seq_att_kernel<<<(B_CNT + 3) / 4, 256, 0, stream>>>(
        finalv, posEmbed, mask, sequence, Wv_seq, att_user);

    pergs_kernel<<<(G_CNT * NS_CNT) / 4, 256, 0, stream>>>(
        finalv, uEmbed, iEmbed, suids, siids, meta2_W, meta2_b, meta3_W, meta3_b,
        uwB, SfB, p1B);

    preds_kernel<<<NPRED / 4, 256, 0, stream>>>(finalv, att_user, uids, iids, uLocs, out);

    ssl_kernel<<<1, 1024, 0, stream>>>(uwB, SfB, p1B, out);
}

// Round 18
// 201.402 us; speedup vs baseline: 1.2445x; 1.2445x over previous
//
#include <hip/hip_runtime.h>
#include <hip/hip_bf16.h>
#include <math.h>

#define G_CNT 4
#define U_CNT 100000
#define I_CNT 50000
#define N_ROWS (U_CNT + I_CNT)
#define D_DIM 64
#define T_STEPS 4
#define L_SEQ 50
#define B_CNT 2048
#define NPRED 8192
#define NS_CNT 4096
#define LEAKY_A 0.5f

typedef short bf16x8 __attribute__((ext_vector_type(8)));
typedef float f32x4 __attribute__((ext_vector_type(4)));

union U16B { unsigned u[4]; bf16x8 v; };

// f32 -> bf16 RNE, pure C (no inline asm)
__device__ __forceinline__ unsigned bfr(float x) {
    unsigned u = __float_as_uint(x);
    return (u + 0x7fffu + ((u >> 16) & 1u)) >> 16;
}
__device__ __forceinline__ unsigned pkbf(float a, float b) {
    return bfr(a) | (bfr(b) << 16);
}
__device__ __forceinline__ float bf_lo(unsigned u) { return __uint_as_float(u << 16); }
__device__ __forceinline__ float bf_hi(unsigned u) { return __uint_as_float(u & 0xffff0000u); }

__device__ __forceinline__ float bcast(float v, int srcLane) {
    return __int_as_float(__builtin_amdgcn_readlane(__float_as_int(v), srcLane));
}

__device__ __forceinline__ float waveReduceSum(float v) {
    v += __shfl_xor(v, 1, 64);
    v += __shfl_xor(v, 2, 64);
    v += __shfl_xor(v, 4, 64);
    v += __shfl_xor(v, 8, 64);
    v += __shfl_xor(v, 16, 64);
    v += __shfl_xor(v, 32, 64);
    return v;
}

__device__ __forceinline__ float waveLayerNorm(float v) {
    float s  = waveReduceSum(v);
    float s2 = waveReduceSum(v * v);
    float mean = s * (1.0f / 64.0f);
    float var  = s2 * (1.0f / 64.0f) - mean * mean;
    return (v - mean) * rsqrtf(var + 1e-5f);
}

// r12 lesson: every f32 divide (no -ffast-math) = ~10-12 VALU instr.
__device__ __forceinline__ float rcp_(float x) { return __builtin_amdgcn_rcpf(x); }

__device__ __forceinline__ float sigm(float x) { return rcp_(1.0f + __expf(-x)); }
__device__ __forceinline__ float tanh_(float x) {
    float xc = fminf(x, 15.0f);
    float t = __expf(2.0f * xc);
    return (t - 1.0f) * rcp_(t + 1.0f);
}
__device__ __forceinline__ float leakyf(float x) { return x >= 0.0f ? x : LEAKY_A * x; }

// Gate-row permutation: lane (r,g)'s output dims == its own B-frag k-slots
// -> h/xn feed the next MFMA B operand as pure register reuse.
__device__ __forceinline__ int gate_perm(int m, int p) {
    int ty = m >> 2, mm = m & 3;
    return ty * 64 + 32 * (mm >> 1) + 8 * (p >> 2) + 4 * (mm & 1) + (p & 3);
}

// ---------------------------------------------------------------------------
// prep_kernel: one-shot pack of weight fragments into d_ws.
// Wih scaled by 3.0 (gates = (3Wih)@emb == Wih@(3emb)).
// ---------------------------------------------------------------------------
__global__ __launch_bounds__(512)
void prep_kernel(const float* __restrict__ Wih, const float* __restrict__ Whh,
                 const float* __restrict__ bih, const float* __restrict__ bhh,
                 const float* __restrict__ Wq0, const float* __restrict__ Wk0, const float* __restrict__ Wv0,
                 const float* __restrict__ Wq1, const float* __restrict__ Wk1, const float* __restrict__ Wv1,
                 char* __restrict__ fragtab, float* __restrict__ biastab)
{
    const int tid  = threadIdx.x;
    const int lane = tid & 63;
    const int wave = tid >> 6;
    const int r    = lane & 15;
    const int g    = lane >> 4;

#pragma unroll
    for (int i = 0; i < 8; ++i) {
        int f = wave * 8 + i;               // 0..63
        int m = f >> 2, kc = f & 3;
        int gate = gate_perm(m, r);
        int k0 = kc * 32 + 8 * g;
        const bool isX = (k0 < 64);
        const float sc = isX ? 3.0f : 1.0f;           // fold x3 into Wih
        const float* src = isX ? (Wih + gate * 64 + k0)
                               : (Whh + gate * 64 + (k0 - 64));
        float4 lo = *(const float4*)src;
        float4 hi = *(const float4*)(src + 4);
        U16B u;
        u.u[0] = pkbf(sc * lo.x, sc * lo.y); u.u[1] = pkbf(sc * lo.z, sc * lo.w);
        u.u[2] = pkbf(sc * hi.x, sc * hi.y); u.u[3] = pkbf(sc * hi.z, sc * hi.w);
        *(bf16x8*)(fragtab + f * 1024 + lane * 16) = u.v;
    }
#pragma unroll
    for (int i = 0; i < 6; ++i) {
        int f = 64 + i * 8 + wave;              // slot = wave = m*2+kc
        int m = (wave >> 1) & 3, kc = wave & 1;
        const float* WM = (i == 0) ? Wq0 : (i == 1) ? Wk0 : (i == 2) ? Wv0
                        : (i == 3) ? Wq1 : (i == 4) ? Wk1 : Wv1;
        int dp = m * 16 + r;
        int k0 = kc * 32 + 8 * g;
        float v0 = WM[(k0 + 0) * 64 + dp], v1 = WM[(k0 + 1) * 64 + dp];
        float v2 = WM[(k0 + 2) * 64 + dp], v3 = WM[(k0 + 3) * 64 + dp];
        float v4 = WM[(k0 + 4) * 64 + dp], v5 = WM[(k0 + 5) * 64 + dp];
        float v6 = WM[(k0 + 6) * 64 + dp], v7 = WM[(k0 + 7) * 64 + dp];
        U16B u;
        u.u[0] = pkbf(v0, v1); u.u[1] = pkbf(v2, v3);
        u.u[2] = pkbf(v4, v5); u.u[3] = pkbf(v6, v7);
        *(bf16x8*)(fragtab + f * 1024 + lane * 16) = u.v;
    }
    if (tid < 256) {
        int m = tid >> 4, p = tid & 15;
        int gate = gate_perm(m, p);
        biastab[tid] = bih[gate] + bhh[gate];
    }
}

// ---------------------------------------------------------------------------
// MFMA tower: 8 waves/block, 16 rows/wave; grid = ceil(N_ROWS/128) = 1172
// (single launch -- r16 lesson: splitting user/item costs a full extra
// block-round via per-CU grid quantization, +25%).
// r16/r17 theory: full unrolling made ~8-10K instructions (64-80KB code)
// >> 32KB L1I; all pipes idle because each cold I$ line stalls at L2
// latency with only 2 waves/SIMD. Fix: REAL t-loop and REAL QKV head-loop
// (#pragma unroll 1) -- code ~4-5x smaller, fits I$; inner mm stays
// unrolled so hp4/cst keep static indices (rule #20).
// xnf in LDS (r15: killed last spill; WRITE_SIZE 37.5MB ideal).
// C/D: col(lane&15)=row, M=4*(lane>>4)+reg [m89-verified].
// ---------------------------------------------------------------------------
__global__ __launch_bounds__(512)
void tower_kernel(const float* __restrict__ uEmbed, const float* __restrict__ iEmbed,
                  const char* __restrict__ fragtab, const float* __restrict__ biastab,
                  float* __restrict__ finalv)
{
    __shared__ char WFRAG[65536];   // LSTM frags 0..63, same layout as fragtab
    __shared__ char XNF[65536];     // per-wave 8KB: xnf[t][c][lane] bf16x8
    __shared__ float BSL[256];

    const int tid  = threadIdx.x;
    const int lane = tid & 63;
    const int wave = tid >> 6;
    const int r    = lane & 15;
    const int g    = lane >> 4;

    // ---- stage LSTM frags + bias into LDS (coalesced 16B/lane copies) ----
#pragma unroll
    for (int i = 0; i < 8; ++i) {
        int off = (wave * 8 + i) * 1024 + lane * 16;
        *(bf16x8*)(WFRAG + off) = *(const bf16x8*)(fragtab + off);
    }
    if (tid < 256) BSL[tid] = biastab[tid];
    __syncthreads();

    const int rowBase0 = blockIdx.x * 128 + wave * 16;
    const bool active  = rowBase0 < N_ROWS;            // wave-uniform (16 | N_ROWS)
    const int rowBase  = active ? rowBase0 : (N_ROWS - 16);
    const bool isUser = rowBase < U_CNT;               // 16 | 100000 -> wave-uniform
    const float* emb = isUser ? uEmbed : iEmbed;
    const int cnt = isUser ? U_CNT : I_CNT;
    const int rloc = (isUser ? rowBase : rowBase - U_CNT) + r;

    char* xnfw = XNF + wave * 8192;     // wave-private xnf stage

    float cst[4][4];
#pragma unroll
    for (int mm = 0; mm < 4; ++mm)
#pragma unroll
        for (int rg = 0; rg < 4; ++rg) cst[mm][rg] = 0.0f;

    uint2 hp4[4];                   // packed h of current step (perm'd dims)

#pragma unroll 1
    for (int t = 0; t < 4; ++t) {
        // ---- x B-frags for this step (raw emb; x3 folded into Wih) ----
        bf16x8 xft[2];
#pragma unroll
        for (int c = 0; c < 2; ++c) {
            const float* p = emb + ((size_t)t * cnt + rloc) * 64 + c * 32 + 8 * g;
            float4 lo = *(const float4*)p;
            float4 hi = *(const float4*)(p + 4);
            U16B u;
            u.u[0] = pkbf(lo.x, lo.y);
            u.u[1] = pkbf(lo.z, lo.w);
            u.u[2] = pkbf(hi.x, hi.y);
            u.u[3] = pkbf(hi.z, hi.w);
            xft[c] = u.v;
        }
        // ---- h B-frags: pure register reuse (gate_perm makes them lane-local)
        bf16x8 hfr[2];
        if (t > 0) {
#pragma unroll
            for (int c = 0; c < 2; ++c) {
                U16B u;
                u.u[0] = hp4[2 * c].x;     u.u[1] = hp4[2 * c].y;
                u.u[2] = hp4[2 * c + 1].x; u.u[3] = hp4[2 * c + 1].y;
                hfr[c] = u.v;
            }
        }
        __builtin_amdgcn_sched_barrier(0);       // B-frags settled

        // ---- per-mm gate groups: only 4 f32x4 accumulators live at once ----
#pragma unroll
        for (int mm = 0; mm < 4; ++mm) {
            f32x4 acc[4];               // ty = i,f,g,o ; gate tile m = ty*4+mm
#pragma unroll
            for (int ty = 0; ty < 4; ++ty)
                acc[ty] = *(const f32x4*)((const char*)BSL + (ty * 4 + mm) * 64 + g * 16);
#pragma unroll
            for (int kc = 0; kc < 2; ++kc)
#pragma unroll
                for (int ty = 0; ty < 4; ++ty) {
                    bf16x8 af = *(const bf16x8*)(WFRAG + ((ty * 4 + mm) * 4 + kc) * 1024 + lane * 16);
                    acc[ty] = __builtin_amdgcn_mfma_f32_16x16x32_bf16(af, xft[kc], acc[ty], 0, 0, 0);
                }
            if (t > 0) {
#pragma unroll
                for (int c = 0; c < 2; ++c)
#pragma unroll
                    for (int ty = 0; ty < 4; ++ty) {
                        bf16x8 af = *(const bf16x8*)(WFRAG + ((ty * 4 + mm) * 4 + 2 + c) * 1024 + lane * 16);
                        acc[ty] = __builtin_amdgcn_mfma_f32_16x16x32_bf16(af, hfr[c], acc[ty], 0, 0, 0);
                    }
            }
            float hv[4];
#pragma unroll
            for (int rg = 0; rg < 4; ++rg) {
                float cc = sigm(acc[1][rg]) * cst[mm][rg] + sigm(acc[0][rg]) * tanh_(acc[2][rg]);
                cst[mm][rg] = cc;
                hv[rg] = sigm(acc[3][rg]) * tanh_(cc);
            }
            hp4[mm].x = pkbf(hv[0], hv[1]);
            hp4[mm].y = pkbf(hv[2], hv[3]);
            __builtin_amdgcn_sched_barrier(0);   // pin mm-group boundary
        }

        // ---- inline LayerNorm; xn frags go straight to LDS (lane-local) ----
        {
            float hv[16];
#pragma unroll
            for (int mm = 0; mm < 4; ++mm) {
                hv[mm * 4 + 0] = bf_lo(hp4[mm].x); hv[mm * 4 + 1] = bf_hi(hp4[mm].x);
                hv[mm * 4 + 2] = bf_lo(hp4[mm].y); hv[mm * 4 + 3] = bf_hi(hp4[mm].y);
            }
            float s = 0.f, s2 = 0.f;
#pragma unroll
            for (int i2 = 0; i2 < 16; ++i2) { s += hv[i2]; s2 += hv[i2] * hv[i2]; }
            s  += __shfl_xor(s, 16, 64);  s  += __shfl_xor(s, 32, 64);
            s2 += __shfl_xor(s2, 16, 64); s2 += __shfl_xor(s2, 32, 64);
            float mean = s * (1.f / 64.f);
            float var  = s2 * (1.f / 64.f) - mean * mean;
            float rs = rsqrtf(var + 1e-5f);
            uint2 xp[4];
#pragma unroll
            for (int mm = 0; mm < 4; ++mm) {
                float x0 = (hv[mm * 4 + 0] - mean) * rs, x1 = (hv[mm * 4 + 1] - mean) * rs;
                float x2 = (hv[mm * 4 + 2] - mean) * rs, x3 = (hv[mm * 4 + 3] - mean) * rs;
                xp[mm].x = pkbf(x0, x1); xp[mm].y = pkbf(x2, x3);
            }
#pragma unroll
            for (int c = 0; c < 2; ++c) {
                U16B u;
                u.u[0] = xp[2 * c].x;     u.u[1] = xp[2 * c].y;
                u.u[2] = xp[2 * c + 1].x; u.u[3] = xp[2 * c + 1].y;
                *(bf16x8*)(xnfw + t * 2048 + c * 1024 + lane * 16) = u.v;
            }
        }
        __builtin_amdgcn_sched_barrier(0);       // pin t-iteration boundary
    }

    // ---- per-head QKV + attention; REAL head loop (code size) ----
    const int base3 = isUser ? 0 : 3;
    float* dst = finalv + (size_t)(rowBase + r) * 64;

#pragma unroll 1
    for (int mm = 0; mm < 4; ++mm) {
        bf16x8 fq[2], fk[2], fv[2];
#pragma unroll
        for (int kc = 0; kc < 2; ++kc) {
            fq[kc] = *(const bf16x8*)(fragtab + (size_t)(64 + (0 + base3) * 8 + mm * 2 + kc) * 1024 + lane * 16);
            fk[kc] = *(const bf16x8*)(fragtab + (size_t)(64 + (1 + base3) * 8 + mm * 2 + kc) * 1024 + lane * 16);
            fv[kc] = *(const bf16x8*)(fragtab + (size_t)(64 + (2 + base3) * 8 + mm * 2 + kc) * 1024 + lane * 16);
        }
        float q[4][4], k[4][4], v[4][4];
#pragma unroll
        for (int t = 0; t < 4; ++t) {
            f32x4 aq = {0.f, 0.f, 0.f, 0.f};
            f32x4 ak = {0.f, 0.f, 0.f, 0.f};
            f32x4 av = {0.f, 0.f, 0.f, 0.f};
#pragma unroll
            for (int kc = 0; kc < 2; ++kc) {
                bf16x8 xn = *(const bf16x8*)(xnfw + t * 2048 + kc * 1024 + lane * 16);
                aq = __builtin_amdgcn_mfma_f32_16x16x32_bf16(fq[kc], xn, aq, 0, 0, 0);
                ak = __builtin_amdgcn_mfma_f32_16x16x32_bf16(fk[kc], xn, ak, 0, 0, 0);
                av = __builtin_amdgcn_mfma_f32_16x16x32_bf16(fv[kc], xn, av, 0, 0, 0);
            }
#pragma unroll
            for (int rg = 0; rg < 4; ++rg) {
                q[t][rg] = aq[rg]; k[t][rg] = ak[rg]; v[t][rg] = av[rg];
            }
        }
        float sc[4][4];                 // [t][s]
#pragma unroll
        for (int t = 0; t < 4; ++t)
#pragma unroll
            for (int s5 = 0; s5 < 4; ++s5) {
                float pr = q[t][0] * k[s5][0] + q[t][1] * k[s5][1]
                         + q[t][2] * k[s5][2] + q[t][3] * k[s5][3];
                pr += __shfl_xor(pr, 16, 64);
                pr += __shfl_xor(pr, 32, 64);
                sc[t][s5] = pr * 0.25f;
            }
        float o0 = 0.f, o1 = 0.f, o2 = 0.f, o3 = 0.f;
#pragma unroll
        for (int t = 0; t < 4; ++t) {
            float mx = fmaxf(fmaxf(sc[t][0], sc[t][1]), fmaxf(sc[t][2], sc[t][3]));
            float e0 = __expf(sc[t][0] - mx), e1 = __expf(sc[t][1] - mx);
            float e2 = __expf(sc[t][2] - mx), e3 = __expf(sc[t][3] - mx);
            float inv = rcp_(e0 + e1 + e2 + e3);
            float a0 = e0 * inv, a1 = e1 * inv, a2 = e2 * inv, a3 = e3 * inv;
            o0 += a0 * v[0][0] + a1 * v[1][0] + a2 * v[2][0] + a3 * v[3][0];
            o1 += a0 * v[0][1] + a1 * v[1][1] + a2 * v[2][1] + a3 * v[3][1];
            o2 += a0 * v[0][2] + a1 * v[1][2] + a2 * v[2][2] + a3 * v[3][2];
            o3 += a0 * v[0][3] + a1 * v[1][3] + a2 * v[2][3] + a3 * v[3][3];
        }
        if (active) {
            float4 o4 = { o0 * 0.25f, o1 * 0.25f, o2 * 0.25f, o3 * 0.25f };
            *(float4*)(dst + mm * 16 + 4 * g) = o4;
        }
    }
}

// ---------------------------------------------------------------------------
// Sequence aggregation + 2 degenerate (T=1) attention layers -> att_user (B,64)
// ---------------------------------------------------------------------------
__global__ __launch_bounds__(256)
void seq_att_kernel(const float* __restrict__ finalv, const float* __restrict__ posEmbed,
                    const float* __restrict__ mask, const int* __restrict__ sequence,
                    const float* __restrict__ Wv_seq, float* __restrict__ att_user)
{
    const int lane = threadIdx.x & 63, wave = threadIdx.x >> 6;
    const int b = blockIdx.x * 4 + wave;
    if (b >= B_CNT) return;
    const float* fitem = finalv + (size_t)U_CNT * D_DIM;

    float acc = 0.0f;
    for (int l = 0; l < L_SEQ; ++l) {
        int   sid = sequence[b * L_SEQ + l];
        float m   = mask[b * L_SEQ + l];
        acc += m * (fitem[(size_t)sid * D_DIM + lane] + posEmbed[l * D_DIM + lane]);
    }
    float att = waveLayerNorm(acc);   // sb
#pragma unroll
    for (int layer = 0; layer < 2; ++layer) {
        float xnv = waveLayerNorm(att);
        float vv = 0.0f;
        const float* Wv = Wv_seq + layer * 64 * 64;
        for (int j = 0; j < 64; ++j)
            vv = fmaf(bcast(xnv, j), Wv[j * 64 + lane], vv);
        att = leakyf(vv) + att;
    }
    att_user[b * D_DIM + lane] = att;
}

// ---------------------------------------------------------------------------
// preds[n] = <fu[uids], fi[iids]> + <leaky(att_user[uLocs]), fi[iids]>
// ---------------------------------------------------------------------------
__global__ __launch_bounds__(256)
void preds_kernel(const float* __restrict__ finalv, const float* __restrict__ att_user,
                  const int* __restrict__ uids, const int* __restrict__ iids,
                  const int* __restrict__ uLocs, float* __restrict__ out)
{
    const int lane = threadIdx.x & 63, wave = threadIdx.x >> 6;
    const int n = blockIdx.x * 4 + wave;
    if (n >= NPRED) return;
    const int u = uids[n], it = iids[n], loc = uLocs[n];
    float fi = finalv[(size_t)(U_CNT + it) * D_DIM + lane];
    float fu = finalv[(size_t)u * D_DIM + lane];
    float au = leakyf(att_user[loc * D_DIM + lane]);
    float p = waveReduceSum(fu * fi + au * fi);
    if (lane == 0) out[n] = p;
}

// ---------------------------------------------------------------------------
// Per (g,s) sample: user_weight (meta MLP), S_final, p1
// ---------------------------------------------------------------------------
__global__ __launch_bounds__(256)
void pergs_kernel(const float* __restrict__ finalv,
                  const float* __restrict__ uEmbed, const float* __restrict__ iEmbed,
                  const int* __restrict__ suids, const int* __restrict__ siids,
                  const float* __restrict__ W2, const float* __restrict__ b2,
                  const float* __restrict__ W3, const float* __restrict__ b3,
                  float* __restrict__ uw, float* __restrict__ SfB, float* __restrict__ p1B)
{
    const int lane = threadIdx.x & 63, wave = threadIdx.x >> 6;
    const int idx = blockIdx.x * 4 + wave;        // 0 .. G*NS-1
    if (idx >= G_CNT * NS_CNT) return;
    const int g  = idx >> 12;                     // NS_CNT == 4096
    const int su = suids[idx], si = siids[idx];

    float fu = finalv[(size_t)su * D_DIM + lane];
    float fi = finalv[(size_t)(U_CNT + si) * D_DIM + lane];
    float uv = 3.0f * uEmbed[((size_t)g * U_CNT + su) * D_DIM + lane];
    float iv = 3.0f * iEmbed[((size_t)g * I_CNT + si) * D_DIM + lane];

    float sf = waveReduceSum(leakyf(fu * fi));
    float pp = waveReduceSum(leakyf(uv * iv));

    float m1a = fu * uv;
    float acc3 = 0.0f;
    for (int o = 0; o < 32; ++o) {
        float part = m1a * W2[o * 192 + lane]
                   + fu  * W2[o * 192 + 64 + lane]
                   + uv  * W2[o * 192 + 128 + lane];
        part = waveReduceSum(part);
        float m2 = leakyf(part + b2[o]);
        acc3 = fmaf(m2, W3[o], acc3);
    }
    float w = rcp_(1.0f + __expf(-(acc3 + b3[0])));
    if (lane == 0) { uw[idx] = w; SfB[idx] = sf; p1B[idx] = pp; }
}

// ---------------------------------------------------------------------------
// Final hinge loss, single block (deterministic)
// ---------------------------------------------------------------------------
__global__ __launch_bounds__(1024)
void ssl_kernel(const float* __restrict__ uw, const float* __restrict__ SfB,
                const float* __restrict__ p1B, float* __restrict__ out)
{
    const int tid = threadIdx.x;
    float local = 0.0f;
    for (int p = tid; p < G_CNT * 2048; p += 1024) {
        int g = p >> 11, s = p & 2047;
        int ip = g * NS_CNT + s, in_ = ip + 2048;
        float Sf   = uw[ip] * SfB[ip] - uw[in_] * SfB[in_];
        float diff = p1B[ip] - p1B[in_];
        local += fmaxf(1.0f - Sf * diff, 0.0f);
    }
    local = waveReduceSum(local);
    __shared__ float part[16];
    const int wave = tid >> 6, lane = tid & 63;
    if (lane == 0) part[wave] = local;
    __syncthreads();
    if (tid == 0) {
        float s = 0.0f;
        for (int i = 0; i < 16; ++i) s += part[i];
        out[NPRED] = s;
    }
}

extern "C" void kernel_launch(void* const* d_in, const int* in_sizes, int n_in,
                              void* d_out, int out_size, void* d_ws, size_t ws_size,
                              hipStream_t stream)
{
    const float* uEmbed  = (const float*)d_in[0];
    const float* iEmbed  = (const float*)d_in[1];
    const float* posEmbed= (const float*)d_in[2];
    const float* Wih     = (const float*)d_in[3];
    const float* Whh     = (const float*)d_in[4];
    const float* bih     = (const float*)d_in[5];
    const float* bhh     = (const float*)d_in[6];
    const float* Wq0     = (const float*)d_in[7];
    const float* Wk0     = (const float*)d_in[8];
    const float* Wv0     = (const float*)d_in[9];
    const float* Wq1     = (const float*)d_in[10];
    const float* Wk1     = (const float*)d_in[11];
    const float* Wv1     = (const float*)d_in[12];
    const float* Wv_seq  = (const float*)d_in[15];
    const float* meta2_W = (const float*)d_in[16];
    const float* meta2_b = (const float*)d_in[17];
    const float* meta3_W = (const float*)d_in[18];
    const float* meta3_b = (const float*)d_in[19];
    const float* mask    = (const float*)d_in[20];
    const int*   uids    = (const int*)d_in[21];
    const int*   iids    = (const int*)d_in[22];
    const int*   sequence= (const int*)d_in[23];
    const int*   uLocs   = (const int*)d_in[24];
    const int*   suids   = (const int*)d_in[25];
    const int*   siids   = (const int*)d_in[26];

    char*  wsB      = (char*)d_ws;
    char*  fragtab  = wsB;                                 // 112KB frags
    float* biastab  = (float*)(wsB + 116 * 1024);          // 1KB bias
    float* finalv   = (float*)(wsB + 128 * 1024);          // N_ROWS*64
    float* att_user = finalv + (size_t)N_ROWS * D_DIM;     // B*64
    float* uwB      = att_user + (size_t)B_CNT * D_DIM;    // G*NS
    float* SfB      = uwB + (size_t)G_CNT * NS_CNT;
    float* p1B      = SfB + (size_t)G_CNT * NS_CNT;
    float* out      = (float*)d_out;

    prep_kernel<<<1, 512, 0, stream>>>(
        Wih, Whh, bih, bhh, Wq0, Wk0, Wv0, Wq1, Wk1, Wv1, fragtab, biastab);

    tower_kernel<<<(N_ROWS + 127) / 128, 512, 0, stream>>>(
        uEmbed, iEmbed, fragtab, biastab, finalv);

    seq_att_kernel<<<(B_CNT + 3) / 4, 256, 0, stream>>>(
        finalv, posEmbed, mask, sequence, Wv_seq, att_user);

    pergs_kernel<<<(G_CNT * NS_CNT) / 4, 256, 0, stream>>>(
        finalv, uEmbed, iEmbed, suids, siids, meta2_W, meta2_b, meta3_W, meta3_b,
        uwB, SfB, p1B);

    preds_kernel<<<NPRED / 4, 256, 0, stream>>>(finalv, att_user, uids, iids, uLocs, out);

    ssl_kernel<<<1, 1024, 0, stream>>>(uwB, SfB, p1B, out);
}

// Round 19
// 195.976 us; speedup vs baseline: 1.2789x; 1.0277x over previous
//
#include <hip/hip_runtime.h>
#include <hip/hip_bf16.h>
#include <math.h>

#define G_CNT 4
#define U_CNT 100000
#define I_CNT 50000
#define N_ROWS (U_CNT + I_CNT)
#define D_DIM 64
#define T_STEPS 4
#define L_SEQ 50
#define B_CNT 2048
#define NPRED 8192
#define NS_CNT 4096
#define LEAKY_A 0.5f

typedef short bf16x8 __attribute__((ext_vector_type(8)));
typedef float f32x4 __attribute__((ext_vector_type(4)));

union U16B { unsigned u[4]; bf16x8 v; };

// f32 -> bf16 RNE, pure C (no inline asm)
__device__ __forceinline__ unsigned bfr(float x) {
    unsigned u = __float_as_uint(x);
    return (u + 0x7fffu + ((u >> 16) & 1u)) >> 16;
}
__device__ __forceinline__ unsigned pkbf(float a, float b) {
    return bfr(a) | (bfr(b) << 16);
}
__device__ __forceinline__ float bf_lo(unsigned u) { return __uint_as_float(u << 16); }
__device__ __forceinline__ float bf_hi(unsigned u) { return __uint_as_float(u & 0xffff0000u); }

__device__ __forceinline__ float bcast(float v, int srcLane) {
    return __int_as_float(__builtin_amdgcn_readlane(__float_as_int(v), srcLane));
}

__device__ __forceinline__ float waveReduceSum(float v) {
    v += __shfl_xor(v, 1, 64);
    v += __shfl_xor(v, 2, 64);
    v += __shfl_xor(v, 4, 64);
    v += __shfl_xor(v, 8, 64);
    v += __shfl_xor(v, 16, 64);
    v += __shfl_xor(v, 32, 64);
    return v;
}

__device__ __forceinline__ float waveLayerNorm(float v) {
    float s  = waveReduceSum(v);
    float s2 = waveReduceSum(v * v);
    float mean = s * (1.0f / 64.0f);
    float var  = s2 * (1.0f / 64.0f) - mean * mean;
    return (v - mean) * rsqrtf(var + 1e-5f);
}

// r12 lesson: every f32 divide (no -ffast-math) = ~10-12 VALU instr.
__device__ __forceinline__ float rcp_(float x) { return __builtin_amdgcn_rcpf(x); }

__device__ __forceinline__ float sigm(float x) { return rcp_(1.0f + __expf(-x)); }
__device__ __forceinline__ float tanh_(float x) {
    float xc = fminf(x, 15.0f);
    float t = __expf(2.0f * xc);
    return (t - 1.0f) * rcp_(t + 1.0f);
}
__device__ __forceinline__ float leakyf(float x) { return x >= 0.0f ? x : LEAKY_A * x; }

// Gate-row permutation: lane (r,g)'s output dims == its own B-frag k-slots
// -> h/xn feed the next MFMA B operand as pure register reuse.
__device__ __forceinline__ int gate_perm(int m, int p) {
    int ty = m >> 2, mm = m & 3;
    return ty * 64 + 32 * (mm >> 1) + 8 * (p >> 2) + 4 * (mm & 1) + (p & 3);
}

// ---------------------------------------------------------------------------
// prep_kernel: one-shot pack of weight fragments into d_ws.
// Wih scaled by 3.0 (gates = (3Wih)@emb == Wih@(3emb)).
// ---------------------------------------------------------------------------
__global__ __launch_bounds__(512)
void prep_kernel(const float* __restrict__ Wih, const float* __restrict__ Whh,
                 const float* __restrict__ bih, const float* __restrict__ bhh,
                 const float* __restrict__ Wq0, const float* __restrict__ Wk0, const float* __restrict__ Wv0,
                 const float* __restrict__ Wq1, const float* __restrict__ Wk1, const float* __restrict__ Wv1,
                 char* __restrict__ fragtab, float* __restrict__ biastab)
{
    const int tid  = threadIdx.x;
    const int lane = tid & 63;
    const int wave = tid >> 6;
    const int r    = lane & 15;
    const int g    = lane >> 4;

#pragma unroll
    for (int i = 0; i < 8; ++i) {
        int f = wave * 8 + i;               // 0..63
        int m = f >> 2, kc = f & 3;
        int gate = gate_perm(m, r);
        int k0 = kc * 32 + 8 * g;
        const bool isX = (k0 < 64);
        const float sc = isX ? 3.0f : 1.0f;           // fold x3 into Wih
        const float* src = isX ? (Wih + gate * 64 + k0)
                               : (Whh + gate * 64 + (k0 - 64));
        float4 lo = *(const float4*)src;
        float4 hi = *(const float4*)(src + 4);
        U16B u;
        u.u[0] = pkbf(sc * lo.x, sc * lo.y); u.u[1] = pkbf(sc * lo.z, sc * lo.w);
        u.u[2] = pkbf(sc * hi.x, sc * hi.y); u.u[3] = pkbf(sc * hi.z, sc * hi.w);
        *(bf16x8*)(fragtab + f * 1024 + lane * 16) = u.v;
    }
#pragma unroll
    for (int i = 0; i < 6; ++i) {
        int f = 64 + i * 8 + wave;              // slot = wave = m*2+kc
        int m = (wave >> 1) & 3, kc = wave & 1;
        const float* WM = (i == 0) ? Wq0 : (i == 1) ? Wk0 : (i == 2) ? Wv0
                        : (i == 3) ? Wq1 : (i == 4) ? Wk1 : Wv1;
        int dp = m * 16 + r;
        int k0 = kc * 32 + 8 * g;
        float v0 = WM[(k0 + 0) * 64 + dp], v1 = WM[(k0 + 1) * 64 + dp];
        float v2 = WM[(k0 + 2) * 64 + dp], v3 = WM[(k0 + 3) * 64 + dp];
        float v4 = WM[(k0 + 4) * 64 + dp], v5 = WM[(k0 + 5) * 64 + dp];
        float v6 = WM[(k0 + 6) * 64 + dp], v7 = WM[(k0 + 7) * 64 + dp];
        U16B u;
        u.u[0] = pkbf(v0, v1); u.u[1] = pkbf(v2, v3);
        u.u[2] = pkbf(v4, v5); u.u[3] = pkbf(v6, v7);
        *(bf16x8*)(fragtab + f * 1024 + lane * 16) = u.v;
    }
    if (tid < 256) {
        int m = tid >> 4, p = tid & 15;
        int gate = gate_perm(m, p);
        biastab[tid] = bih[gate] + bhh[gate];
    }
}

// ---------------------------------------------------------------------------
// MFMA tower: 8 waves/block, 16 rows/wave; grid = ceil(N_ROWS/128) = 1172
// (single launch; r16: splitting costs a block-round). Real t/head loops
// (r17: I$ fit; tower 208->165us). xnf in LDS (r15: no spill). LN computed
// on f32 h (matches reference; deletes 16 unpacks/t).
// C/D: col(lane&15)=row, M=4*(lane>>4)+reg [m89-verified].
// ---------------------------------------------------------------------------
__global__ __launch_bounds__(512)
void tower_kernel(const float* __restrict__ uEmbed, const float* __restrict__ iEmbed,
                  const char* __restrict__ fragtab, const float* __restrict__ biastab,
                  float* __restrict__ finalv)
{
    __shared__ char WFRAG[65536];   // LSTM frags 0..63, same layout as fragtab
    __shared__ char XNF[65536];     // per-wave 8KB: xnf[t][c][lane] bf16x8
    __shared__ float BSL[256];

    const int tid  = threadIdx.x;
    const int lane = tid & 63;
    const int wave = tid >> 6;
    const int r    = lane & 15;
    const int g    = lane >> 4;

    // ---- stage LSTM frags + bias into LDS (coalesced 16B/lane copies) ----
#pragma unroll
    for (int i = 0; i < 8; ++i) {
        int off = (wave * 8 + i) * 1024 + lane * 16;
        *(bf16x8*)(WFRAG + off) = *(const bf16x8*)(fragtab + off);
    }
    if (tid < 256) BSL[tid] = biastab[tid];
    __syncthreads();

    const int rowBase0 = blockIdx.x * 128 + wave * 16;
    const bool active  = rowBase0 < N_ROWS;            // wave-uniform (16 | N_ROWS)
    const int rowBase  = active ? rowBase0 : (N_ROWS - 16);
    const bool isUser = rowBase < U_CNT;               // 16 | 100000 -> wave-uniform
    const float* emb = isUser ? uEmbed : iEmbed;
    const int cnt = isUser ? U_CNT : I_CNT;
    const int rloc = (isUser ? rowBase : rowBase - U_CNT) + r;

    char* xnfw = XNF + wave * 8192;     // wave-private xnf stage

    float cst[4][4];
#pragma unroll
    for (int mm = 0; mm < 4; ++mm)
#pragma unroll
        for (int rg = 0; rg < 4; ++rg) cst[mm][rg] = 0.0f;

    uint2 hp4[4];                   // packed h of current step (perm'd dims)

#pragma unroll 1
    for (int t = 0; t < 4; ++t) {
        // ---- x B-frags for this step (raw emb; x3 folded into Wih) ----
        bf16x8 xft[2];
#pragma unroll
        for (int c = 0; c < 2; ++c) {
            const float* p = emb + ((size_t)t * cnt + rloc) * 64 + c * 32 + 8 * g;
            float4 lo = *(const float4*)p;
            float4 hi = *(const float4*)(p + 4);
            U16B u;
            u.u[0] = pkbf(lo.x, lo.y);
            u.u[1] = pkbf(lo.z, lo.w);
            u.u[2] = pkbf(hi.x, hi.y);
            u.u[3] = pkbf(hi.z, hi.w);
            xft[c] = u.v;
        }
        // ---- h B-frags: pure register reuse (gate_perm makes them lane-local)
        bf16x8 hfr[2];
        if (t > 0) {
#pragma unroll
            for (int c = 0; c < 2; ++c) {
                U16B u;
                u.u[0] = hp4[2 * c].x;     u.u[1] = hp4[2 * c].y;
                u.u[2] = hp4[2 * c + 1].x; u.u[3] = hp4[2 * c + 1].y;
                hfr[c] = u.v;
            }
        }
        __builtin_amdgcn_sched_barrier(0);       // B-frags settled

        // ---- per-mm gate groups; h kept in f32 (hvall) for LN ----
        float hvall[16];
#pragma unroll
        for (int mm = 0; mm < 4; ++mm) {
            f32x4 acc[4];               // ty = i,f,g,o ; gate tile m = ty*4+mm
#pragma unroll
            for (int ty = 0; ty < 4; ++ty)
                acc[ty] = *(const f32x4*)((const char*)BSL + (ty * 4 + mm) * 64 + g * 16);
#pragma unroll
            for (int kc = 0; kc < 2; ++kc)
#pragma unroll
                for (int ty = 0; ty < 4; ++ty) {
                    bf16x8 af = *(const bf16x8*)(WFRAG + ((ty * 4 + mm) * 4 + kc) * 1024 + lane * 16);
                    acc[ty] = __builtin_amdgcn_mfma_f32_16x16x32_bf16(af, xft[kc], acc[ty], 0, 0, 0);
                }
            if (t > 0) {
#pragma unroll
                for (int c = 0; c < 2; ++c)
#pragma unroll
                    for (int ty = 0; ty < 4; ++ty) {
                        bf16x8 af = *(const bf16x8*)(WFRAG + ((ty * 4 + mm) * 4 + 2 + c) * 1024 + lane * 16);
                        acc[ty] = __builtin_amdgcn_mfma_f32_16x16x32_bf16(af, hfr[c], acc[ty], 0, 0, 0);
                    }
            }
#pragma unroll
            for (int rg = 0; rg < 4; ++rg) {
                float cc = sigm(acc[1][rg]) * cst[mm][rg] + sigm(acc[0][rg]) * tanh_(acc[2][rg]);
                cst[mm][rg] = cc;
                hvall[mm * 4 + rg] = sigm(acc[3][rg]) * tanh_(cc);
            }
            __builtin_amdgcn_sched_barrier(0);   // pin mm-group boundary
        }

        // ---- LN on f32 h; pack hp4 (next-step h frags) + xn frags to LDS ----
        {
            float s = 0.f, s2 = 0.f;
#pragma unroll
            for (int i2 = 0; i2 < 16; ++i2) { s += hvall[i2]; s2 += hvall[i2] * hvall[i2]; }
            s  += __shfl_xor(s, 16, 64);  s  += __shfl_xor(s, 32, 64);
            s2 += __shfl_xor(s2, 16, 64); s2 += __shfl_xor(s2, 32, 64);
            float mean = s * (1.f / 64.f);
            float var  = s2 * (1.f / 64.f) - mean * mean;
            float rs = rsqrtf(var + 1e-5f);
            uint2 xp[4];
#pragma unroll
            for (int mm = 0; mm < 4; ++mm) {
                hp4[mm].x = pkbf(hvall[mm * 4 + 0], hvall[mm * 4 + 1]);
                hp4[mm].y = pkbf(hvall[mm * 4 + 2], hvall[mm * 4 + 3]);
                float x0 = (hvall[mm * 4 + 0] - mean) * rs, x1 = (hvall[mm * 4 + 1] - mean) * rs;
                float x2 = (hvall[mm * 4 + 2] - mean) * rs, x3 = (hvall[mm * 4 + 3] - mean) * rs;
                xp[mm].x = pkbf(x0, x1); xp[mm].y = pkbf(x2, x3);
            }
#pragma unroll
            for (int c = 0; c < 2; ++c) {
                U16B u;
                u.u[0] = xp[2 * c].x;     u.u[1] = xp[2 * c].y;
                u.u[2] = xp[2 * c + 1].x; u.u[3] = xp[2 * c + 1].y;
                *(bf16x8*)(xnfw + t * 2048 + c * 1024 + lane * 16) = u.v;
            }
        }
        __builtin_amdgcn_sched_barrier(0);       // pin t-iteration boundary
    }

    // ---- per-head QKV + attention; REAL head loop (code size) ----
    const int base3 = isUser ? 0 : 3;
    float* dst = finalv + (size_t)(rowBase + r) * 64;

#pragma unroll 1
    for (int mm = 0; mm < 4; ++mm) {
        bf16x8 fq[2], fk[2], fv[2];
#pragma unroll
        for (int kc = 0; kc < 2; ++kc) {
            fq[kc] = *(const bf16x8*)(fragtab + (size_t)(64 + (0 + base3) * 8 + mm * 2 + kc) * 1024 + lane * 16);
            fk[kc] = *(const bf16x8*)(fragtab + (size_t)(64 + (1 + base3) * 8 + mm * 2 + kc) * 1024 + lane * 16);
            fv[kc] = *(const bf16x8*)(fragtab + (size_t)(64 + (2 + base3) * 8 + mm * 2 + kc) * 1024 + lane * 16);
        }
        float q[4][4], k[4][4], v[4][4];
#pragma unroll
        for (int t = 0; t < 4; ++t) {
            f32x4 aq = {0.f, 0.f, 0.f, 0.f};
            f32x4 ak = {0.f, 0.f, 0.f, 0.f};
            f32x4 av = {0.f, 0.f, 0.f, 0.f};
#pragma unroll
            for (int kc = 0; kc < 2; ++kc) {
                bf16x8 xn = *(const bf16x8*)(xnfw + t * 2048 + kc * 1024 + lane * 16);
                aq = __builtin_amdgcn_mfma_f32_16x16x32_bf16(fq[kc], xn, aq, 0, 0, 0);
                ak = __builtin_amdgcn_mfma_f32_16x16x32_bf16(fk[kc], xn, ak, 0, 0, 0);
                av = __builtin_amdgcn_mfma_f32_16x16x32_bf16(fv[kc], xn, av, 0, 0, 0);
            }
#pragma unroll
            for (int rg = 0; rg < 4; ++rg) {
                q[t][rg] = aq[rg]; k[t][rg] = ak[rg]; v[t][rg] = av[rg];
            }
        }
        float sc[4][4];                 // [t][s]
#pragma unroll
        for (int t = 0; t < 4; ++t)
#pragma unroll
            for (int s5 = 0; s5 < 4; ++s5) {
                float pr = q[t][0] * k[s5][0] + q[t][1] * k[s5][1]
                         + q[t][2] * k[s5][2] + q[t][3] * k[s5][3];
                pr += __shfl_xor(pr, 16, 64);
                pr += __shfl_xor(pr, 32, 64);
                sc[t][s5] = pr * 0.25f;
            }
        float o0 = 0.f, o1 = 0.f, o2 = 0.f, o3 = 0.f;
#pragma unroll
        for (int t = 0; t < 4; ++t) {
            float mx = fmaxf(fmaxf(sc[t][0], sc[t][1]), fmaxf(sc[t][2], sc[t][3]));
            float e0 = __expf(sc[t][0] - mx), e1 = __expf(sc[t][1] - mx);
            float e2 = __expf(sc[t][2] - mx), e3 = __expf(sc[t][3] - mx);
            float inv = rcp_(e0 + e1 + e2 + e3);
            float a0 = e0 * inv, a1 = e1 * inv, a2 = e2 * inv, a3 = e3 * inv;
            o0 += a0 * v[0][0] + a1 * v[1][0] + a2 * v[2][0] + a3 * v[3][0];
            o1 += a0 * v[0][1] + a1 * v[1][1] + a2 * v[2][1] + a3 * v[3][1];
            o2 += a0 * v[0][2] + a1 * v[1][2] + a2 * v[2][2] + a3 * v[3][2];
            o3 += a0 * v[0][3] + a1 * v[1][3] + a2 * v[2][3] + a3 * v[3][3];
        }
        if (active) {
            float4 o4 = { o0 * 0.25f, o1 * 0.25f, o2 * 0.25f, o3 * 0.25f };
            *(float4*)(dst + mm * 16 + 4 * g) = o4;
        }
    }
}

// ---------------------------------------------------------------------------
// Fused tail kernel 1: seq_att (blocks 0..511) + pergs (blocks 512..4607).
// Both depend only on finalv -> safe in one launch.
// ---------------------------------------------------------------------------
__global__ __launch_bounds__(256)
void seq_pergs_kernel(const float* __restrict__ finalv, const float* __restrict__ posEmbed,
                      const float* __restrict__ mask, const int* __restrict__ sequence,
                      const float* __restrict__ Wv_seq, float* __restrict__ att_user,
                      const float* __restrict__ uEmbed, const float* __restrict__ iEmbed,
                      const int* __restrict__ suids, const int* __restrict__ siids,
                      const float* __restrict__ W2, const float* __restrict__ b2,
                      const float* __restrict__ W3, const float* __restrict__ b3,
                      float* __restrict__ uw, float* __restrict__ SfB, float* __restrict__ p1B)
{
    const int lane = threadIdx.x & 63, wave = threadIdx.x >> 6;

    if (blockIdx.x < B_CNT / 4) {
        // ---------------- seq_att ----------------
        const int b = blockIdx.x * 4 + wave;
        const float* fitem = finalv + (size_t)U_CNT * D_DIM;

        float acc = 0.0f;
        for (int l = 0; l < L_SEQ; ++l) {
            int   sid = sequence[b * L_SEQ + l];
            float m   = mask[b * L_SEQ + l];
            acc += m * (fitem[(size_t)sid * D_DIM + lane] + posEmbed[l * D_DIM + lane]);
        }
        float att = waveLayerNorm(acc);   // sb
#pragma unroll
        for (int layer = 0; layer < 2; ++layer) {
            float xnv = waveLayerNorm(att);
            float vv = 0.0f;
            const float* Wv = Wv_seq + layer * 64 * 64;
            for (int j = 0; j < 64; ++j)
                vv = fmaf(bcast(xnv, j), Wv[j * 64 + lane], vv);
            att = leakyf(vv) + att;
        }
        att_user[b * D_DIM + lane] = att;
    } else {
        // ---------------- pergs ----------------
        const int idx = (blockIdx.x - B_CNT / 4) * 4 + wave;   // 0 .. G*NS-1
        const int g  = idx >> 12;                              // NS_CNT == 4096
        const int su = suids[idx], si = siids[idx];

        float fu = finalv[(size_t)su * D_DIM + lane];
        float fi = finalv[(size_t)(U_CNT + si) * D_DIM + lane];
        float uv = 3.0f * uEmbed[((size_t)g * U_CNT + su) * D_DIM + lane];
        float iv = 3.0f * iEmbed[((size_t)g * I_CNT + si) * D_DIM + lane];

        float sf = waveReduceSum(leakyf(fu * fi));
        float pp = waveReduceSum(leakyf(uv * iv));

        float m1a = fu * uv;
        float acc3 = 0.0f;
        for (int o = 0; o < 32; ++o) {
            float part = m1a * W2[o * 192 + lane]
                       + fu  * W2[o * 192 + 64 + lane]
                       + uv  * W2[o * 192 + 128 + lane];
            part = waveReduceSum(part);
            float m2 = leakyf(part + b2[o]);
            acc3 = fmaf(m2, W3[o], acc3);
        }
        float w = rcp_(1.0f + __expf(-(acc3 + b3[0])));
        if (lane == 0) { uw[idx] = w; SfB[idx] = sf; p1B[idx] = pp; }
    }
}

// ---------------------------------------------------------------------------
// Fused tail kernel 2: preds (blocks 0..2047) + ssl (block 2048).
// ssl reads pergs outputs written by the previous kernel -> ordering OK.
// ---------------------------------------------------------------------------
__global__ __launch_bounds__(256)
void preds_ssl_kernel(const float* __restrict__ finalv, const float* __restrict__ att_user,
                      const int* __restrict__ uids, const int* __restrict__ iids,
                      const int* __restrict__ uLocs,
                      const float* __restrict__ uw, const float* __restrict__ SfB,
                      const float* __restrict__ p1B, float* __restrict__ out)
{
    const int lane = threadIdx.x & 63, wave = threadIdx.x >> 6;

    if (blockIdx.x < NPRED / 4) {
        const int n = blockIdx.x * 4 + wave;
        const int u = uids[n], it = iids[n], loc = uLocs[n];
        float fi = finalv[(size_t)(U_CNT + it) * D_DIM + lane];
        float fu = finalv[(size_t)u * D_DIM + lane];
        float au = leakyf(att_user[loc * D_DIM + lane]);
        float p = waveReduceSum(fu * fi + au * fi);
        if (lane == 0) out[n] = p;
    } else {
        // ---------------- ssl (single block, deterministic) ----------------
        const int tid = threadIdx.x;
        float local = 0.0f;
        for (int p = tid; p < G_CNT * 2048; p += 256) {
            int g = p >> 11, s = p & 2047;
            int ip = g * NS_CNT + s, in_ = ip + 2048;
            float Sf   = uw[ip] * SfB[ip] - uw[in_] * SfB[in_];
            float diff = p1B[ip] - p1B[in_];
            local += fmaxf(1.0f - Sf * diff, 0.0f);
        }
        local = waveReduceSum(local);
        __shared__ float part[4];
        if (lane == 0) part[wave] = local;
        __syncthreads();
        if (tid == 0) {
            float s = part[0] + part[1] + part[2] + part[3];
            out[NPRED] = s;
        }
    }
}

extern "C" void kernel_launch(void* const* d_in, const int* in_sizes, int n_in,
                              void* d_out, int out_size, void* d_ws, size_t ws_size,
                              hipStream_t stream)
{
    const float* uEmbed  = (const float*)d_in[0];
    const float* iEmbed  = (const float*)d_in[1];
    const float* posEmbed= (const float*)d_in[2];
    const float* Wih     = (const float*)d_in[3];
    const float* Whh     = (const float*)d_in[4];
    const float* bih     = (const float*)d_in[5];
    const float* bhh     = (const float*)d_in[6];
    const float* Wq0     = (const float*)d_in[7];
    const float* Wk0     = (const float*)d_in[8];
    const float* Wv0     = (const float*)d_in[9];
    const float* Wq1     = (const float*)d_in[10];
    const float* Wk1     = (const float*)d_in[11];
    const float* Wv1     = (const float*)d_in[12];
    const float* Wv_seq  = (const float*)d_in[15];
    const float* meta2_W = (const float*)d_in[16];
    const float* meta2_b = (const float*)d_in[17];
    const float* meta3_W = (const float*)d_in[18];
    const float* meta3_b = (const float*)d_in[19];
    const float* mask    = (const float*)d_in[20];
    const int*   uids    = (const int*)d_in[21];
    const int*   iids    = (const int*)d_in[22];
    const int*   sequence= (const int*)d_in[23];
    const int*   uLocs   = (const int*)d_in[24];
    const int*   suids   = (const int*)d_in[25];
    const int*   siids   = (const int*)d_in[26];

    char*  wsB      = (char*)d_ws;
    char*  fragtab  = wsB;                                 // 112KB frags
    float* biastab  = (float*)(wsB + 116 * 1024);          // 1KB bias
    float* finalv   = (float*)(wsB + 128 * 1024);          // N_ROWS*64
    float* att_user = finalv + (size_t)N_ROWS * D_DIM;     // B*64
    float* uwB      = att_user + (size_t)B_CNT * D_DIM;    // G*NS
    float* SfB      = uwB + (size_t)G_CNT * NS_CNT;
    float* p1B      = SfB + (size_t)G_CNT * NS_CNT;
    float* out      = (float*)d_out;

    prep_kernel<<<1, 512, 0, stream>>>(
        Wih, Whh, bih, bhh, Wq0, Wk0, Wv0, Wq1, Wk1, Wv1, fragtab, biastab);

    tower_kernel<<<(N_ROWS + 127) / 128, 512, 0, stream>>>(
        uEmbed, iEmbed, fragtab, biastab, finalv);

    seq_pergs_kernel<<<B_CNT / 4 + (G_CNT * NS_CNT) / 4, 256, 0, stream>>>(
        finalv, posEmbed, mask, sequence, Wv_seq, att_user,
        uEmbed, iEmbed, suids, siids, meta2_W, meta2_b, meta3_W, meta3_b,
        uwB, SfB, p1B);

    preds_ssl_kernel<<<NPRED / 4 + 1, 256, 0, stream>>>(
        finalv, att_user, uids, iids, uLocs, uwB, SfB, p1B, out);
}

// Round 20
// 192.229 us; speedup vs baseline: 1.3039x; 1.0195x over previous
//
#include <hip/hip_runtime.h>
#include <hip/hip_bf16.h>
#include <math.h>

#define G_CNT 4
#define U_CNT 100000
#define I_CNT 50000
#define N_ROWS (U_CNT + I_CNT)
#define D_DIM 64
#define T_STEPS 4
#define L_SEQ 50
#define B_CNT 2048
#define NPRED 8192
#define NS_CNT 4096
#define LEAKY_A 0.5f

typedef short bf16x8 __attribute__((ext_vector_type(8)));
typedef float f32x4 __attribute__((ext_vector_type(4)));

union U16B { unsigned u[4]; bf16x8 v; };

// f32 -> bf16 RNE, pure C (no inline asm)
__device__ __forceinline__ unsigned bfr(float x) {
    unsigned u = __float_as_uint(x);
    return (u + 0x7fffu + ((u >> 16) & 1u)) >> 16;
}
__device__ __forceinline__ unsigned pkbf(float a, float b) {
    return bfr(a) | (bfr(b) << 16);
}
__device__ __forceinline__ float bf_lo(unsigned u) { return __uint_as_float(u << 16); }
__device__ __forceinline__ float bf_hi(unsigned u) { return __uint_as_float(u & 0xffff0000u); }

__device__ __forceinline__ float bcast(float v, int srcLane) {
    return __int_as_float(__builtin_amdgcn_readlane(__float_as_int(v), srcLane));
}

__device__ __forceinline__ float waveReduceSum(float v) {
    v += __shfl_xor(v, 1, 64);
    v += __shfl_xor(v, 2, 64);
    v += __shfl_xor(v, 4, 64);
    v += __shfl_xor(v, 8, 64);
    v += __shfl_xor(v, 16, 64);
    v += __shfl_xor(v, 32, 64);
    return v;
}

__device__ __forceinline__ float waveLayerNorm(float v) {
    float s  = waveReduceSum(v);
    float s2 = waveReduceSum(v * v);
    float mean = s * (1.0f / 64.0f);
    float var  = s2 * (1.0f / 64.0f) - mean * mean;
    return (v - mean) * rsqrtf(var + 1e-5f);
}

// r12 lesson: every f32 divide (no -ffast-math) = ~10-12 VALU instr.
__device__ __forceinline__ float rcp_(float x) { return __builtin_amdgcn_rcpf(x); }

__device__ __forceinline__ float sigm(float x) { return rcp_(1.0f + __expf(-x)); }
__device__ __forceinline__ float tanh_(float x) {
    float xc = fminf(x, 15.0f);
    float t = __expf(2.0f * xc);
    return (t - 1.0f) * rcp_(t + 1.0f);
}
__device__ __forceinline__ float leakyf(float x) { return x >= 0.0f ? x : LEAKY_A * x; }

// Gate-row permutation: lane (r,g)'s output dims == its own B-frag k-slots
// -> h/xn feed the next MFMA B operand as pure register reuse.
__device__ __forceinline__ int gate_perm(int m, int p) {
    int ty = m >> 2, mm = m & 3;
    return ty * 64 + 32 * (mm >> 1) + 8 * (p >> 2) + 4 * (mm & 1) + (p & 3);
}

// ---------------------------------------------------------------------------
// prep_kernel: one-shot pack of weight fragments into d_ws.
// Wih scaled by 3.0 (gates = (3Wih)@emb == Wih@(3emb)).
// ---------------------------------------------------------------------------
__global__ __launch_bounds__(512)
void prep_kernel(const float* __restrict__ Wih, const float* __restrict__ Whh,
                 const float* __restrict__ bih, const float* __restrict__ bhh,
                 const float* __restrict__ Wq0, const float* __restrict__ Wk0, const float* __restrict__ Wv0,
                 const float* __restrict__ Wq1, const float* __restrict__ Wk1, const float* __restrict__ Wv1,
                 char* __restrict__ fragtab, float* __restrict__ biastab)
{
    const int tid  = threadIdx.x;
    const int lane = tid & 63;
    const int wave = tid >> 6;
    const int r    = lane & 15;
    const int g    = lane >> 4;

#pragma unroll
    for (int i = 0; i < 8; ++i) {
        int f = wave * 8 + i;               // 0..63
        int m = f >> 2, kc = f & 3;
        int gate = gate_perm(m, r);
        int k0 = kc * 32 + 8 * g;
        const bool isX = (k0 < 64);
        const float sc = isX ? 3.0f : 1.0f;           // fold x3 into Wih
        const float* src = isX ? (Wih + gate * 64 + k0)
                               : (Whh + gate * 64 + (k0 - 64));
        float4 lo = *(const float4*)src;
        float4 hi = *(const float4*)(src + 4);
        U16B u;
        u.u[0] = pkbf(sc * lo.x, sc * lo.y); u.u[1] = pkbf(sc * lo.z, sc * lo.w);
        u.u[2] = pkbf(sc * hi.x, sc * hi.y); u.u[3] = pkbf(sc * hi.z, sc * hi.w);
        *(bf16x8*)(fragtab + f * 1024 + lane * 16) = u.v;
    }
#pragma unroll
    for (int i = 0; i < 6; ++i) {
        int f = 64 + i * 8 + wave;              // slot = wave = m*2+kc
        int m = (wave >> 1) & 3, kc = wave & 1;
        const float* WM = (i == 0) ? Wq0 : (i == 1) ? Wk0 : (i == 2) ? Wv0
                        : (i == 3) ? Wq1 : (i == 4) ? Wk1 : Wv1;
        int dp = m * 16 + r;
        int k0 = kc * 32 + 8 * g;
        float v0 = WM[(k0 + 0) * 64 + dp], v1 = WM[(k0 + 1) * 64 + dp];
        float v2 = WM[(k0 + 2) * 64 + dp], v3 = WM[(k0 + 3) * 64 + dp];
        float v4 = WM[(k0 + 4) * 64 + dp], v5 = WM[(k0 + 5) * 64 + dp];
        float v6 = WM[(k0 + 6) * 64 + dp], v7 = WM[(k0 + 7) * 64 + dp];
        U16B u;
        u.u[0] = pkbf(v0, v1); u.u[1] = pkbf(v2, v3);
        u.u[2] = pkbf(v4, v5); u.u[3] = pkbf(v6, v7);
        *(bf16x8*)(fragtab + f * 1024 + lane * 16) = u.v;
    }
    if (tid < 256) {
        int m = tid >> 4, p = tid & 15;
        int gate = gate_perm(m, p);
        biastab[tid] = bih[gate] + bhh[gate];
    }
}

// ---------------------------------------------------------------------------
// MFMA tower: 8 waves/block, 16 rows/wave; grid = ceil(N_ROWS/128) = 1172.
// Real t/head loops (r17: I$ fit). xnf in LDS (r15: no spill). LN on f32 h.
// r19: fused-rcp gate math (5 rcp -> 3 rcp per dim; trans pipe is the
// largest remaining slice) + mm-group sched_barrier removed (40-reg
// headroom lets scheduler overlap adjacent mm groups; WRITE_SIZE guards
// against spill).
// C/D: col(lane&15)=row, M=4*(lane>>4)+reg [m89-verified].
// ---------------------------------------------------------------------------
__global__ __launch_bounds__(512)
void tower_kernel(const float* __restrict__ uEmbed, const float* __restrict__ iEmbed,
                  const char* __restrict__ fragtab, const float* __restrict__ biastab,
                  float* __restrict__ finalv)
{
    __shared__ char WFRAG[65536];   // LSTM frags 0..63, same layout as fragtab
    __shared__ char XNF[65536];     // per-wave 8KB: xnf[t][c][lane] bf16x8
    __shared__ float BSL[256];

    const int tid  = threadIdx.x;
    const int lane = tid & 63;
    const int wave = tid >> 6;
    const int r    = lane & 15;
    const int g    = lane >> 4;

    // ---- stage LSTM frags + bias into LDS (coalesced 16B/lane copies) ----
#pragma unroll
    for (int i = 0; i < 8; ++i) {
        int off = (wave * 8 + i) * 1024 + lane * 16;
        *(bf16x8*)(WFRAG + off) = *(const bf16x8*)(fragtab + off);
    }
    if (tid < 256) BSL[tid] = biastab[tid];
    __syncthreads();

    const int rowBase0 = blockIdx.x * 128 + wave * 16;
    const bool active  = rowBase0 < N_ROWS;            // wave-uniform (16 | N_ROWS)
    const int rowBase  = active ? rowBase0 : (N_ROWS - 16);
    const bool isUser = rowBase < U_CNT;               // 16 | 100000 -> wave-uniform
    const float* emb = isUser ? uEmbed : iEmbed;
    const int cnt = isUser ? U_CNT : I_CNT;
    const int rloc = (isUser ? rowBase : rowBase - U_CNT) + r;

    char* xnfw = XNF + wave * 8192;     // wave-private xnf stage

    float cst[4][4];
#pragma unroll
    for (int mm = 0; mm < 4; ++mm)
#pragma unroll
        for (int rg = 0; rg < 4; ++rg) cst[mm][rg] = 0.0f;

    uint2 hp4[4];                   // packed h of current step (perm'd dims)

#pragma unroll 1
    for (int t = 0; t < 4; ++t) {
        // ---- x B-frags for this step (raw emb; x3 folded into Wih) ----
        bf16x8 xft[2];
#pragma unroll
        for (int c = 0; c < 2; ++c) {
            const float* p = emb + ((size_t)t * cnt + rloc) * 64 + c * 32 + 8 * g;
            float4 lo = *(const float4*)p;
            float4 hi = *(const float4*)(p + 4);
            U16B u;
            u.u[0] = pkbf(lo.x, lo.y);
            u.u[1] = pkbf(lo.z, lo.w);
            u.u[2] = pkbf(hi.x, hi.y);
            u.u[3] = pkbf(hi.z, hi.w);
            xft[c] = u.v;
        }
        // ---- h B-frags: pure register reuse (gate_perm makes them lane-local)
        bf16x8 hfr[2];
        if (t > 0) {
#pragma unroll
            for (int c = 0; c < 2; ++c) {
                U16B u;
                u.u[0] = hp4[2 * c].x;     u.u[1] = hp4[2 * c].y;
                u.u[2] = hp4[2 * c + 1].x; u.u[3] = hp4[2 * c + 1].y;
                hfr[c] = u.v;
            }
        }
        __builtin_amdgcn_sched_barrier(0);       // B-frags settled

        // ---- per-mm gate groups; h kept in f32 (hvall) for LN ----
        float hvall[16];
#pragma unroll
        for (int mm = 0; mm < 4; ++mm) {
            f32x4 acc[4];               // ty = i,f,g,o ; gate tile m = ty*4+mm
#pragma unroll
            for (int ty = 0; ty < 4; ++ty)
                acc[ty] = *(const f32x4*)((const char*)BSL + (ty * 4 + mm) * 64 + g * 16);
#pragma unroll
            for (int kc = 0; kc < 2; ++kc)
#pragma unroll
                for (int ty = 0; ty < 4; ++ty) {
                    bf16x8 af = *(const bf16x8*)(WFRAG + ((ty * 4 + mm) * 4 + kc) * 1024 + lane * 16);
                    acc[ty] = __builtin_amdgcn_mfma_f32_16x16x32_bf16(af, xft[kc], acc[ty], 0, 0, 0);
                }
            if (t > 0) {
#pragma unroll
                for (int c = 0; c < 2; ++c)
#pragma unroll
                    for (int ty = 0; ty < 4; ++ty) {
                        bf16x8 af = *(const bf16x8*)(WFRAG + ((ty * 4 + mm) * 4 + 2 + c) * 1024 + lane * 16);
                        acc[ty] = __builtin_amdgcn_mfma_f32_16x16x32_bf16(af, hfr[c], acc[ty], 0, 0, 0);
                    }
            }
            // fused-rcp gates: cc = c*rcp(1+e_f) + (tg-1)*rcp((1+e_i)(tg+1));
            //                   h = (tc-1)*rcp((1+e_o)(tc+1))
#pragma unroll
            for (int rg = 0; rg < 4; ++rg) {
                float ei = __expf(-acc[0][rg]);
                float ef = __expf(-acc[1][rg]);
                float tg = __expf(2.0f * fminf(acc[2][rg], 15.0f));
                float eo = __expf(-acc[3][rg]);
                float cc = cst[mm][rg] * rcp_(1.0f + ef)
                         + (tg - 1.0f) * rcp_((1.0f + ei) * (tg + 1.0f));
                cst[mm][rg] = cc;
                float tc = __expf(2.0f * fminf(cc, 15.0f));
                hvall[mm * 4 + rg] = (tc - 1.0f) * rcp_((1.0f + eo) * (tc + 1.0f));
            }
        }
        __builtin_amdgcn_sched_barrier(0);       // gate phase done

        // ---- LN on f32 h; pack hp4 (next-step h frags) + xn frags to LDS ----
        {
            float s = 0.f, s2 = 0.f;
#pragma unroll
            for (int i2 = 0; i2 < 16; ++i2) { s += hvall[i2]; s2 += hvall[i2] * hvall[i2]; }
            s  += __shfl_xor(s, 16, 64);  s  += __shfl_xor(s, 32, 64);
            s2 += __shfl_xor(s2, 16, 64); s2 += __shfl_xor(s2, 32, 64);
            float mean = s * (1.f / 64.f);
            float var  = s2 * (1.f / 64.f) - mean * mean;
            float rs = rsqrtf(var + 1e-5f);
            uint2 xp[4];
#pragma unroll
            for (int mm = 0; mm < 4; ++mm) {
                hp4[mm].x = pkbf(hvall[mm * 4 + 0], hvall[mm * 4 + 1]);
                hp4[mm].y = pkbf(hvall[mm * 4 + 2], hvall[mm * 4 + 3]);
                float x0 = (hvall[mm * 4 + 0] - mean) * rs, x1 = (hvall[mm * 4 + 1] - mean) * rs;
                float x2 = (hvall[mm * 4 + 2] - mean) * rs, x3 = (hvall[mm * 4 + 3] - mean) * rs;
                xp[mm].x = pkbf(x0, x1); xp[mm].y = pkbf(x2, x3);
            }
#pragma unroll
            for (int c = 0; c < 2; ++c) {
                U16B u;
                u.u[0] = xp[2 * c].x;     u.u[1] = xp[2 * c].y;
                u.u[2] = xp[2 * c + 1].x; u.u[3] = xp[2 * c + 1].y;
                *(bf16x8*)(xnfw + t * 2048 + c * 1024 + lane * 16) = u.v;
            }
        }
        __builtin_amdgcn_sched_barrier(0);       // pin t-iteration boundary
    }

    // ---- per-head QKV + attention; REAL head loop (code size) ----
    const int base3 = isUser ? 0 : 3;
    float* dst = finalv + (size_t)(rowBase + r) * 64;

#pragma unroll 1
    for (int mm = 0; mm < 4; ++mm) {
        bf16x8 fq[2], fk[2], fv[2];
#pragma unroll
        for (int kc = 0; kc < 2; ++kc) {
            fq[kc] = *(const bf16x8*)(fragtab + (size_t)(64 + (0 + base3) * 8 + mm * 2 + kc) * 1024 + lane * 16);
            fk[kc] = *(const bf16x8*)(fragtab + (size_t)(64 + (1 + base3) * 8 + mm * 2 + kc) * 1024 + lane * 16);
            fv[kc] = *(const bf16x8*)(fragtab + (size_t)(64 + (2 + base3) * 8 + mm * 2 + kc) * 1024 + lane * 16);
        }
        float q[4][4], k[4][4], v[4][4];
#pragma unroll
        for (int t = 0; t < 4; ++t) {
            f32x4 aq = {0.f, 0.f, 0.f, 0.f};
            f32x4 ak = {0.f, 0.f, 0.f, 0.f};
            f32x4 av = {0.f, 0.f, 0.f, 0.f};
#pragma unroll
            for (int kc = 0; kc < 2; ++kc) {
                bf16x8 xn = *(const bf16x8*)(xnfw + t * 2048 + kc * 1024 + lane * 16);
                aq = __builtin_amdgcn_mfma_f32_16x16x32_bf16(fq[kc], xn, aq, 0, 0, 0);
                ak = __builtin_amdgcn_mfma_f32_16x16x32_bf16(fk[kc], xn, ak, 0, 0, 0);
                av = __builtin_amdgcn_mfma_f32_16x16x32_bf16(fv[kc], xn, av, 0, 0, 0);
            }
#pragma unroll
            for (int rg = 0; rg < 4; ++rg) {
                q[t][rg] = aq[rg]; k[t][rg] = ak[rg]; v[t][rg] = av[rg];
            }
        }
        float sc[4][4];                 // [t][s]
#pragma unroll
        for (int t = 0; t < 4; ++t)
#pragma unroll
            for (int s5 = 0; s5 < 4; ++s5) {
                float pr = q[t][0] * k[s5][0] + q[t][1] * k[s5][1]
                         + q[t][2] * k[s5][2] + q[t][3] * k[s5][3];
                pr += __shfl_xor(pr, 16, 64);
                pr += __shfl_xor(pr, 32, 64);
                sc[t][s5] = pr * 0.25f;
            }
        float o0 = 0.f, o1 = 0.f, o2 = 0.f, o3 = 0.f;
#pragma unroll
        for (int t = 0; t < 4; ++t) {
            float mx = fmaxf(fmaxf(sc[t][0], sc[t][1]), fmaxf(sc[t][2], sc[t][3]));
            float e0 = __expf(sc[t][0] - mx), e1 = __expf(sc[t][1] - mx);
            float e2 = __expf(sc[t][2] - mx), e3 = __expf(sc[t][3] - mx);
            float inv = rcp_(e0 + e1 + e2 + e3);
            float a0 = e0 * inv, a1 = e1 * inv, a2 = e2 * inv, a3 = e3 * inv;
            o0 += a0 * v[0][0] + a1 * v[1][0] + a2 * v[2][0] + a3 * v[3][0];
            o1 += a0 * v[0][1] + a1 * v[1][1] + a2 * v[2][1] + a3 * v[3][1];
            o2 += a0 * v[0][2] + a1 * v[1][2] + a2 * v[2][2] + a3 * v[3][2];
            o3 += a0 * v[0][3] + a1 * v[1][3] + a2 * v[2][3] + a3 * v[3][3];
        }
        if (active) {
            float4 o4 = { o0 * 0.25f, o1 * 0.25f, o2 * 0.25f, o3 * 0.25f };
            *(float4*)(dst + mm * 16 + 4 * g) = o4;
        }
    }
}

// ---------------------------------------------------------------------------
// Fused tail kernel 1: seq_att (blocks 0..511) + pergs (blocks 512..4607).
// Both depend only on finalv -> safe in one launch.
// ---------------------------------------------------------------------------
__global__ __launch_bounds__(256)
void seq_pergs_kernel(const float* __restrict__ finalv, const float* __restrict__ posEmbed,
                      const float* __restrict__ mask, const int* __restrict__ sequence,
                      const float* __restrict__ Wv_seq, float* __restrict__ att_user,
                      const float* __restrict__ uEmbed, const float* __restrict__ iEmbed,
                      const int* __restrict__ suids, const int* __restrict__ siids,
                      const float* __restrict__ W2, const float* __restrict__ b2,
                      const float* __restrict__ W3, const float* __restrict__ b3,
                      float* __restrict__ uw, float* __restrict__ SfB, float* __restrict__ p1B)
{
    const int lane = threadIdx.x & 63, wave = threadIdx.x >> 6;

    if (blockIdx.x < B_CNT / 4) {
        // ---------------- seq_att ----------------
        const int b = blockIdx.x * 4 + wave;
        const float* fitem = finalv + (size_t)U_CNT * D_DIM;

        float acc = 0.0f;
        for (int l = 0; l < L_SEQ; ++l) {
            int   sid = sequence[b * L_SEQ + l];
            float m   = mask[b * L_SEQ + l];
            acc += m * (fitem[(size_t)sid * D_DIM + lane] + posEmbed[l * D_DIM + lane]);
        }
        float att = waveLayerNorm(acc);   // sb
#pragma unroll
        for (int layer = 0; layer < 2; ++layer) {
            float xnv = waveLayerNorm(att);
            float vv = 0.0f;
            const float* Wv = Wv_seq + layer * 64 * 64;
            for (int j = 0; j < 64; ++j)
                vv = fmaf(bcast(xnv, j), Wv[j * 64 + lane], vv);
            att = leakyf(vv) + att;
        }
        att_user[b * D_DIM + lane] = att;
    } else {
        // ---------------- pergs ----------------
        const int idx = (blockIdx.x - B_CNT / 4) * 4 + wave;   // 0 .. G*NS-1
        const int g  = idx >> 12;                              // NS_CNT == 4096
        const int su = suids[idx], si = siids[idx];

        float fu = finalv[(size_t)su * D_DIM + lane];
        float fi = finalv[(size_t)(U_CNT + si) * D_DIM + lane];
        float uv = 3.0f * uEmbed[((size_t)g * U_CNT + su) * D_DIM + lane];
        float iv = 3.0f * iEmbed[((size_t)g * I_CNT + si) * D_DIM + lane];

        float sf = waveReduceSum(leakyf(fu * fi));
        float pp = waveReduceSum(leakyf(uv * iv));

        float m1a = fu * uv;
        float acc3 = 0.0f;
        for (int o = 0; o < 32; ++o) {
            float part = m1a * W2[o * 192 + lane]
                       + fu  * W2[o * 192 + 64 + lane]
                       + uv  * W2[o * 192 + 128 + lane];
            part = waveReduceSum(part);
            float m2 = leakyf(part + b2[o]);
            acc3 = fmaf(m2, W3[o], acc3);
        }
        float w = rcp_(1.0f + __expf(-(acc3 + b3[0])));
        if (lane == 0) { uw[idx] = w; SfB[idx] = sf; p1B[idx] = pp; }
    }
}

// ---------------------------------------------------------------------------
// Fused tail kernel 2: preds (blocks 0..2047) + ssl (block 2048).
// ssl reads pergs outputs written by the previous kernel -> ordering OK.
// ---------------------------------------------------------------------------
__global__ __launch_bounds__(256)
void preds_ssl_kernel(const float* __restrict__ finalv, const float* __restrict__ att_user,
                      const int* __restrict__ uids, const int* __restrict__ iids,
                      const int* __restrict__ uLocs,
                      const float* __restrict__ uw, const float* __restrict__ SfB,
                      const float* __restrict__ p1B, float* __restrict__ out)
{
    const int lane = threadIdx.x & 63, wave = threadIdx.x >> 6;

    if (blockIdx.x < NPRED / 4) {
        const int n = blockIdx.x * 4 + wave;
        const int u = uids[n], it = iids[n], loc = uLocs[n];
        float fi = finalv[(size_t)(U_CNT + it) * D_DIM + lane];
        float fu = finalv[(size_t)u * D_DIM + lane];
        float au = leakyf(att_user[loc * D_DIM + lane]);
        float p = waveReduceSum(fu * fi + au * fi);
        if (lane == 0) out[n] = p;
    } else {
        // ---------------- ssl (single block, deterministic) ----------------
        const int tid = threadIdx.x;
        float local = 0.0f;
        for (int p = tid; p < G_CNT * 2048; p += 256) {
            int g = p >> 11, s = p & 2047;
            int ip = g * NS_CNT + s, in_ = ip + 2048;
            float Sf   = uw[ip] * SfB[ip] - uw[in_] * SfB[in_];
            float diff = p1B[ip] - p1B[in_];
            local += fmaxf(1.0f - Sf * diff, 0.0f);
        }
        local = waveReduceSum(local);
        __shared__ float part[4];
        if (lane == 0) part[wave] = local;
        __syncthreads();
        if (tid == 0) {
            float s = part[0] + part[1] + part[2] + part[3];
            out[NPRED] = s;
        }
    }
}

extern "C" void kernel_launch(void* const* d_in, const int* in_sizes, int n_in,
                              void* d_out, int out_size, void* d_ws, size_t ws_size,
                              hipStream_t stream)
{
    const float* uEmbed  = (const float*)d_in[0];
    const float* iEmbed  = (const float*)d_in[1];
    const float* posEmbed= (const float*)d_in[2];
    const float* Wih     = (const float*)d_in[3];
    const float* Whh     = (const float*)d_in[4];
    const float* bih     = (const float*)d_in[5];
    const float* bhh     = (const float*)d_in[6];
    const float* Wq0     = (const float*)d_in[7];
    const float* Wk0     = (const float*)d_in[8];
    const float* Wv0     = (const float*)d_in[9];
    const float* Wq1     = (const float*)d_in[10];
    const float* Wk1     = (const float*)d_in[11];
    const float* Wv1     = (const float*)d_in[12];
    const float* Wv_seq  = (const float*)d_in[15];
    const float* meta2_W = (const float*)d_in[16];
    const float* meta2_b = (const float*)d_in[17];
    const float* meta3_W = (const float*)d_in[18];
    const float* meta3_b = (const float*)d_in[19];
    const float* mask    = (const float*)d_in[20];
    const int*   uids    = (const int*)d_in[21];
    const int*   iids    = (const int*)d_in[22];
    const int*   sequence= (const int*)d_in[23];
    const int*   uLocs   = (const int*)d_in[24];
    const int*   suids   = (const int*)d_in[25];
    const int*   siids   = (const int*)d_in[26];

    char*  wsB      = (char*)d_ws;
    char*  fragtab  = wsB;                                 // 112KB frags
    float* biastab  = (float*)(wsB + 116 * 1024);          // 1KB bias
    float* finalv   = (float*)(wsB + 128 * 1024);          // N_ROWS*64
    float* att_user = finalv + (size_t)N_ROWS * D_DIM;     // B*64
    float* uwB      = att_user + (size_t)B_CNT * D_DIM;    // G*NS
    float* SfB      = uwB + (size_t)G_CNT * NS_CNT;
    float* p1B      = SfB + (size_t)G_CNT * NS_CNT;
    float* out      = (float*)d_out;

    prep_kernel<<<1, 512, 0, stream>>>(
        Wih, Whh, bih, bhh, Wq0, Wk0, Wv0, Wq1, Wk1, Wv1, fragtab, biastab);

    tower_kernel<<<(N_ROWS + 127) / 128, 512, 0, stream>>>(
        uEmbed, iEmbed, fragtab, biastab, finalv);

    seq_pergs_kernel<<<B_CNT / 4 + (G_CNT * NS_CNT) / 4, 256, 0, stream>>>(
        finalv, posEmbed, mask, sequence, Wv_seq, att_user,
        uEmbed, iEmbed, suids, siids, meta2_W, meta2_b, meta3_W, meta3_b,
        uwB, SfB, p1B);

    preds_ssl_kernel<<<NPRED / 4 + 1, 256, 0, stream>>>(
        finalv, att_user, uids, iids, uLocs, uwB, SfB, p1B, out);
}

// Round 22
// 189.599 us; speedup vs baseline: 1.3220x; 1.0139x over previous
//
#include <hip/hip_runtime.h>
#include <hip/hip_bf16.h>
#include <math.h>

#define G_CNT 4
#define U_CNT 100000
#define I_CNT 50000
#define N_ROWS (U_CNT + I_CNT)
#define D_DIM 64
#define T_STEPS 4
#define L_SEQ 50
#define B_CNT 2048
#define NPRED 8192
#define NS_CNT 4096
#define LEAKY_A 0.5f

typedef short bf16x8 __attribute__((ext_vector_type(8)));
typedef float f32x4 __attribute__((ext_vector_type(4)));

union U16B { unsigned u[4]; bf16x8 v; };

// f32x2 -> packed bf16x2 via HW v_cvt_pk_bf16_f32 (safe C++ path, no asm).
// __hip_bfloat162 is not trivially copyable -> extract via the POD raw type.
__device__ __forceinline__ unsigned pkbf(float a, float b) {
    __hip_bfloat162 t = __float22bfloat162_rn(float2{a, b});
    __hip_bfloat162_raw rw = t;             // POD: {unsigned short x, y}
    return (unsigned)rw.x | ((unsigned)rw.y << 16);
}
__device__ __forceinline__ float bf_lo(unsigned u) { return __uint_as_float(u << 16); }
__device__ __forceinline__ float bf_hi(unsigned u) { return __uint_as_float(u & 0xffff0000u); }

__device__ __forceinline__ float bcast(float v, int srcLane) {
    return __int_as_float(__builtin_amdgcn_readlane(__float_as_int(v), srcLane));
}

__device__ __forceinline__ float waveReduceSum(float v) {
    v += __shfl_xor(v, 1, 64);
    v += __shfl_xor(v, 2, 64);
    v += __shfl_xor(v, 4, 64);
    v += __shfl_xor(v, 8, 64);
    v += __shfl_xor(v, 16, 64);
    v += __shfl_xor(v, 32, 64);
    return v;
}

__device__ __forceinline__ float waveLayerNorm(float v) {
    float s  = waveReduceSum(v);
    float s2 = waveReduceSum(v * v);
    float mean = s * (1.0f / 64.0f);
    float var  = s2 * (1.0f / 64.0f) - mean * mean;
    return (v - mean) * rsqrtf(var + 1e-5f);
}

// r12 lesson: every f32 divide (no -ffast-math) = ~10-12 VALU instr.
__device__ __forceinline__ float rcp_(float x) { return __builtin_amdgcn_rcpf(x); }

__device__ __forceinline__ float sigm(float x) { return rcp_(1.0f + __expf(-x)); }
__device__ __forceinline__ float tanh_(float x) {
    float xc = fminf(x, 15.0f);
    float t = __expf(2.0f * xc);
    return (t - 1.0f) * rcp_(t + 1.0f);
}
__device__ __forceinline__ float leakyf(float x) { return x >= 0.0f ? x : LEAKY_A * x; }

// Gate-row permutation: lane (r,g)'s output dims == its own B-frag k-slots
// -> h/xn feed the next MFMA B operand as pure register reuse.
__device__ __forceinline__ int gate_perm(int m, int p) {
    int ty = m >> 2, mm = m & 3;
    return ty * 64 + 32 * (mm >> 1) + 8 * (p >> 2) + 4 * (mm & 1) + (p & 3);
}

// ---------------------------------------------------------------------------
// prep_kernel: one-shot pack of weight fragments into d_ws.
// Wih scaled by 3.0 (gates = (3Wih)@emb == Wih@(3emb)).
// ---------------------------------------------------------------------------
__global__ __launch_bounds__(512)
void prep_kernel(const float* __restrict__ Wih, const float* __restrict__ Whh,
                 const float* __restrict__ bih, const float* __restrict__ bhh,
                 const float* __restrict__ Wq0, const float* __restrict__ Wk0, const float* __restrict__ Wv0,
                 const float* __restrict__ Wq1, const float* __restrict__ Wk1, const float* __restrict__ Wv1,
                 char* __restrict__ fragtab, float* __restrict__ biastab)
{
    const int tid  = threadIdx.x;
    const int lane = tid & 63;
    const int wave = tid >> 6;
    const int r    = lane & 15;
    const int g    = lane >> 4;

#pragma unroll
    for (int i = 0; i < 8; ++i) {
        int f = wave * 8 + i;               // 0..63
        int m = f >> 2, kc = f & 3;
        int gate = gate_perm(m, r);
        int k0 = kc * 32 + 8 * g;
        const bool isX = (k0 < 64);
        const float sc = isX ? 3.0f : 1.0f;           // fold x3 into Wih
        const float* src = isX ? (Wih + gate * 64 + k0)
                               : (Whh + gate * 64 + (k0 - 64));
        float4 lo = *(const float4*)src;
        float4 hi = *(const float4*)(src + 4);
        U16B u;
        u.u[0] = pkbf(sc * lo.x, sc * lo.y); u.u[1] = pkbf(sc * lo.z, sc * lo.w);
        u.u[2] = pkbf(sc * hi.x, sc * hi.y); u.u[3] = pkbf(sc * hi.z, sc * hi.w);
        *(bf16x8*)(fragtab + f * 1024 + lane * 16) = u.v;
    }
#pragma unroll
    for (int i = 0; i < 6; ++i) {
        int f = 64 + i * 8 + wave;              // slot = wave = m*2+kc
        int m = (wave >> 1) & 3, kc = wave & 1;
        const float* WM = (i == 0) ? Wq0 : (i == 1) ? Wk0 : (i == 2) ? Wv0
                        : (i == 3) ? Wq1 : (i == 4) ? Wk1 : Wv1;
        int dp = m * 16 + r;
        int k0 = kc * 32 + 8 * g;
        float v0 = WM[(k0 + 0) * 64 + dp], v1 = WM[(k0 + 1) * 64 + dp];
        float v2 = WM[(k0 + 2) * 64 + dp], v3 = WM[(k0 + 3) * 64 + dp];
        float v4 = WM[(k0 + 4) * 64 + dp], v5 = WM[(k0 + 5) * 64 + dp];
        float v6 = WM[(k0 + 6) * 64 + dp], v7 = WM[(k0 + 7) * 64 + dp];
        U16B u;
        u.u[0] = pkbf(v0, v1); u.u[1] = pkbf(v2, v3);
        u.u[2] = pkbf(v4, v5); u.u[3] = pkbf(v6, v7);
        *(bf16x8*)(fragtab + f * 1024 + lane * 16) = u.v;
    }
    if (tid < 256) {
        int m = tid >> 4, p = tid & 15;
        int gate = gate_perm(m, p);
        biastab[tid] = bih[gate] + bhh[gate];
    }
}

// ---------------------------------------------------------------------------
// MFMA tower: 8 waves/block, 16 rows/wave; grid = ceil(N_ROWS/128) = 1172.
// Real t/head loops (r17: I$ fit). xnf in LDS (r15: no spill). LN on f32 h.
// r20/r21: HW cvt_pk packing (-~600 VALU instr/lane) + single-rcp cc.
// C/D: col(lane&15)=row, M=4*(lane>>4)+reg [m89-verified].
// ---------------------------------------------------------------------------
__global__ __launch_bounds__(512)
void tower_kernel(const float* __restrict__ uEmbed, const float* __restrict__ iEmbed,
                  const char* __restrict__ fragtab, const float* __restrict__ biastab,
                  float* __restrict__ finalv)
{
    __shared__ char WFRAG[65536];   // LSTM frags 0..63, same layout as fragtab
    __shared__ char XNF[65536];     // per-wave 8KB: xnf[t][c][lane] bf16x8
    __shared__ float BSL[256];

    const int tid  = threadIdx.x;
    const int lane = tid & 63;
    const int wave = tid >> 6;
    const int r    = lane & 15;
    const int g    = lane >> 4;

    // ---- stage LSTM frags + bias into LDS (coalesced 16B/lane copies) ----
#pragma unroll
    for (int i = 0; i < 8; ++i) {
        int off = (wave * 8 + i) * 1024 + lane * 16;
        *(bf16x8*)(WFRAG + off) = *(const bf16x8*)(fragtab + off);
    }
    if (tid < 256) BSL[tid] = biastab[tid];
    __syncthreads();

    const int rowBase0 = blockIdx.x * 128 + wave * 16;
    const bool active  = rowBase0 < N_ROWS;            // wave-uniform (16 | N_ROWS)
    const int rowBase  = active ? rowBase0 : (N_ROWS - 16);
    const bool isUser = rowBase < U_CNT;               // 16 | 100000 -> wave-uniform
    const float* emb = isUser ? uEmbed : iEmbed;
    const int cnt = isUser ? U_CNT : I_CNT;
    const int rloc = (isUser ? rowBase : rowBase - U_CNT) + r;

    char* xnfw = XNF + wave * 8192;     // wave-private xnf stage

    float cst[4][4];
#pragma unroll
    for (int mm = 0; mm < 4; ++mm)
#pragma unroll
        for (int rg = 0; rg < 4; ++rg) cst[mm][rg] = 0.0f;

    uint2 hp4[4];                   // packed h of current step (perm'd dims)

#pragma unroll 1
    for (int t = 0; t < 4; ++t) {
        // ---- x B-frags for this step (raw emb; x3 folded into Wih) ----
        bf16x8 xft[2];
#pragma unroll
        for (int c = 0; c < 2; ++c) {
            const float* p = emb + ((size_t)t * cnt + rloc) * 64 + c * 32 + 8 * g;
            float4 lo = *(const float4*)p;
            float4 hi = *(const float4*)(p + 4);
            U16B u;
            u.u[0] = pkbf(lo.x, lo.y);
            u.u[1] = pkbf(lo.z, lo.w);
            u.u[2] = pkbf(hi.x, hi.y);
            u.u[3] = pkbf(hi.z, hi.w);
            xft[c] = u.v;
        }
        // ---- h B-frags: pure register reuse (gate_perm makes them lane-local)
        bf16x8 hfr[2];
        if (t > 0) {
#pragma unroll
            for (int c = 0; c < 2; ++c) {
                U16B u;
                u.u[0] = hp4[2 * c].x;     u.u[1] = hp4[2 * c].y;
                u.u[2] = hp4[2 * c + 1].x; u.u[3] = hp4[2 * c + 1].y;
                hfr[c] = u.v;
            }
        }
        __builtin_amdgcn_sched_barrier(0);       // B-frags settled

        // ---- per-mm gate groups; h kept in f32 (hvall) for LN ----
        float hvall[16];
#pragma unroll
        for (int mm = 0; mm < 4; ++mm) {
            f32x4 acc[4];               // ty = i,f,g,o ; gate tile m = ty*4+mm
#pragma unroll
            for (int ty = 0; ty < 4; ++ty)
                acc[ty] = *(const f32x4*)((const char*)BSL + (ty * 4 + mm) * 64 + g * 16);
#pragma unroll
            for (int kc = 0; kc < 2; ++kc)
#pragma unroll
                for (int ty = 0; ty < 4; ++ty) {
                    bf16x8 af = *(const bf16x8*)(WFRAG + ((ty * 4 + mm) * 4 + kc) * 1024 + lane * 16);
                    acc[ty] = __builtin_amdgcn_mfma_f32_16x16x32_bf16(af, xft[kc], acc[ty], 0, 0, 0);
                }
            if (t > 0) {
#pragma unroll
                for (int c = 0; c < 2; ++c)
#pragma unroll
                    for (int ty = 0; ty < 4; ++ty) {
                        bf16x8 af = *(const bf16x8*)(WFRAG + ((ty * 4 + mm) * 4 + 2 + c) * 1024 + lane * 16);
                        acc[ty] = __builtin_amdgcn_mfma_f32_16x16x32_bf16(af, hfr[c], acc[ty], 0, 0, 0);
                    }
            }
            // single-rcp cc: cc = [c(1+ei)(tg+1) + (tg-1)(1+ef)] * rcp((1+ef)(1+ei)(tg+1))
            // h = (tc-1) * rcp((1+eo)(tc+1))
#pragma unroll
            for (int rg = 0; rg < 4; ++rg) {
                float ei = __expf(-acc[0][rg]);
                float ef = __expf(-acc[1][rg]);
                float tg = __expf(2.0f * fminf(acc[2][rg], 15.0f));
                float eo = __expf(-acc[3][rg]);
                float a1 = 1.0f + ei, a2 = 1.0f + ef, a3 = tg + 1.0f, a4 = tg - 1.0f;
                float t13 = a1 * a3;
                float num = fmaf(cst[mm][rg], t13, a4 * a2);
                float cc  = num * rcp_(a2 * t13);
                cst[mm][rg] = cc;
                float tc = __expf(2.0f * fminf(cc, 15.0f));
                hvall[mm * 4 + rg] = (tc - 1.0f) * rcp_((1.0f + eo) * (tc + 1.0f));
            }
        }
        __builtin_amdgcn_sched_barrier(0);       // gate phase done

        // ---- LN on f32 h; pack hp4 (next-step h frags) + xn frags to LDS ----
        {
            float s = 0.f, s2 = 0.f;
#pragma unroll
            for (int i2 = 0; i2 < 16; ++i2) { s += hvall[i2]; s2 += hvall[i2] * hvall[i2]; }
            s  += __shfl_xor(s, 16, 64);  s  += __shfl_xor(s, 32, 64);
            s2 += __shfl_xor(s2, 16, 64); s2 += __shfl_xor(s2, 32, 64);
            float mean = s * (1.f / 64.f);
            float var  = s2 * (1.f / 64.f) - mean * mean;
            float rs = rsqrtf(var + 1e-5f);
            uint2 xp[4];
#pragma unroll
            for (int mm = 0; mm < 4; ++mm) {
                hp4[mm].x = pkbf(hvall[mm * 4 + 0], hvall[mm * 4 + 1]);
                hp4[mm].y = pkbf(hvall[mm * 4 + 2], hvall[mm * 4 + 3]);
                float x0 = (hvall[mm * 4 + 0] - mean) * rs, x1 = (hvall[mm * 4 + 1] - mean) * rs;
                float x2 = (hvall[mm * 4 + 2] - mean) * rs, x3 = (hvall[mm * 4 + 3] - mean) * rs;
                xp[mm].x = pkbf(x0, x1); xp[mm].y = pkbf(x2, x3);
            }
#pragma unroll
            for (int c = 0; c < 2; ++c) {
                U16B u;
                u.u[0] = xp[2 * c].x;     u.u[1] = xp[2 * c].y;
                u.u[2] = xp[2 * c + 1].x; u.u[3] = xp[2 * c + 1].y;
                *(bf16x8*)(xnfw + t * 2048 + c * 1024 + lane * 16) = u.v;
            }
        }
        __builtin_amdgcn_sched_barrier(0);       // pin t-iteration boundary
    }

    // ---- per-head QKV + attention; REAL head loop (code size) ----
    const int base3 = isUser ? 0 : 3;
    float* dst = finalv + (size_t)(rowBase + r) * 64;

#pragma unroll 1
    for (int mm = 0; mm < 4; ++mm) {
        bf16x8 fq[2], fk[2], fv[2];
#pragma unroll
        for (int kc = 0; kc < 2; ++kc) {
            fq[kc] = *(const bf16x8*)(fragtab + (size_t)(64 + (0 + base3) * 8 + mm * 2 + kc) * 1024 + lane * 16);
            fk[kc] = *(const bf16x8*)(fragtab + (size_t)(64 + (1 + base3) * 8 + mm * 2 + kc) * 1024 + lane * 16);
            fv[kc] = *(const bf16x8*)(fragtab + (size_t)(64 + (2 + base3) * 8 + mm * 2 + kc) * 1024 + lane * 16);
        }
        float q[4][4], k[4][4], v[4][4];
#pragma unroll
        for (int t = 0; t < 4; ++t) {
            f32x4 aq = {0.f, 0.f, 0.f, 0.f};
            f32x4 ak = {0.f, 0.f, 0.f, 0.f};
            f32x4 av = {0.f, 0.f, 0.f, 0.f};
#pragma unroll
            for (int kc = 0; kc < 2; ++kc) {
                bf16x8 xn = *(const bf16x8*)(xnfw + t * 2048 + kc * 1024 + lane * 16);
                aq = __builtin_amdgcn_mfma_f32_16x16x32_bf16(fq[kc], xn, aq, 0, 0, 0);
                ak = __builtin_amdgcn_mfma_f32_16x16x32_bf16(fk[kc], xn, ak, 0, 0, 0);
                av = __builtin_amdgcn_mfma_f32_16x16x32_bf16(fv[kc], xn, av, 0, 0, 0);
            }
#pragma unroll
            for (int rg = 0; rg < 4; ++rg) {
                q[t][rg] = aq[rg]; k[t][rg] = ak[rg]; v[t][rg] = av[rg];
            }
        }
        float sc[4][4];                 // [t][s]
#pragma unroll
        for (int t = 0; t < 4; ++t)
#pragma unroll
            for (int s5 = 0; s5 < 4; ++s5) {
                float pr = q[t][0] * k[s5][0] + q[t][1] * k[s5][1]
                         + q[t][2] * k[s5][2] + q[t][3] * k[s5][3];
                pr += __shfl_xor(pr, 16, 64);
                pr += __shfl_xor(pr, 32, 64);
                sc[t][s5] = pr * 0.25f;
            }
        float o0 = 0.f, o1 = 0.f, o2 = 0.f, o3 = 0.f;
#pragma unroll
        for (int t = 0; t < 4; ++t) {
            float mx = fmaxf(fmaxf(sc[t][0], sc[t][1]), fmaxf(sc[t][2], sc[t][3]));
            float e0 = __expf(sc[t][0] - mx), e1 = __expf(sc[t][1] - mx);
            float e2 = __expf(sc[t][2] - mx), e3 = __expf(sc[t][3] - mx);
            float inv = rcp_(e0 + e1 + e2 + e3);
            float a0 = e0 * inv, a1 = e1 * inv, a2 = e2 * inv, a3 = e3 * inv;
            o0 += a0 * v[0][0] + a1 * v[1][0] + a2 * v[2][0] + a3 * v[3][0];
            o1 += a0 * v[0][1] + a1 * v[1][1] + a2 * v[2][1] + a3 * v[3][1];
            o2 += a0 * v[0][2] + a1 * v[1][2] + a2 * v[2][2] + a3 * v[3][2];
            o3 += a0 * v[0][3] + a1 * v[1][3] + a2 * v[2][3] + a3 * v[3][3];
        }
        if (active) {
            float4 o4 = { o0 * 0.25f, o1 * 0.25f, o2 * 0.25f, o3 * 0.25f };
            *(float4*)(dst + mm * 16 + 4 * g) = o4;
        }
    }
}

// ---------------------------------------------------------------------------
// Fused tail kernel 1: seq_att (blocks 0..511) + pergs (blocks 512..4607).
// Both depend only on finalv -> safe in one launch.
// ---------------------------------------------------------------------------
__global__ __launch_bounds__(256)
void seq_pergs_kernel(const float* __restrict__ finalv, const float* __restrict__ posEmbed,
                      const float* __restrict__ mask, const int* __restrict__ sequence,
                      const float* __restrict__ Wv_seq, float* __restrict__ att_user,
                      const float* __restrict__ uEmbed, const float* __restrict__ iEmbed,
                      const int* __restrict__ suids, const int* __restrict__ siids,
                      const float* __restrict__ W2, const float* __restrict__ b2,
                      const float* __restrict__ W3, const float* __restrict__ b3,
                      float* __restrict__ uw, float* __restrict__ SfB, float* __restrict__ p1B)
{
    const int lane = threadIdx.x & 63, wave = threadIdx.x >> 6;

    if (blockIdx.x < B_CNT / 4) {
        // ---------------- seq_att ----------------
        const int b = blockIdx.x * 4 + wave;
        const float* fitem = finalv + (size_t)U_CNT * D_DIM;

        float acc = 0.0f;
        for (int l = 0; l < L_SEQ; ++l) {
            int   sid = sequence[b * L_SEQ + l];
            float m   = mask[b * L_SEQ + l];
            acc += m * (fitem[(size_t)sid * D_DIM + lane] + posEmbed[l * D_DIM + lane]);
        }
        float att = waveLayerNorm(acc);   // sb
#pragma unroll
        for (int layer = 0; layer < 2; ++layer) {
            float xnv = waveLayerNorm(att);
            float vv = 0.0f;
            const float* Wv = Wv_seq + layer * 64 * 64;
            for (int j = 0; j < 64; ++j)
                vv = fmaf(bcast(xnv, j), Wv[j * 64 + lane], vv);
            att = leakyf(vv) + att;
        }
        att_user[b * D_DIM + lane] = att;
    } else {
        // ---------------- pergs ----------------
        const int idx = (blockIdx.x - B_CNT / 4) * 4 + wave;   // 0 .. G*NS-1
        const int g  = idx >> 12;                              // NS_CNT == 4096
        const int su = suids[idx], si = siids[idx];

        float fu = finalv[(size_t)su * D_DIM + lane];
        float fi = finalv[(size_t)(U_CNT + si) * D_DIM + lane];
        float uv = 3.0f * uEmbed[((size_t)g * U_CNT + su) * D_DIM + lane];
        float iv = 3.0f * iEmbed[((size_t)g * I_CNT + si) * D_DIM + lane];

        float sf = waveReduceSum(leakyf(fu * fi));
        float pp = waveReduceSum(leakyf(uv * iv));

        float m1a = fu * uv;
        float acc3 = 0.0f;
        for (int o = 0; o < 32; ++o) {
            float part = m1a * W2[o * 192 + lane]
                       + fu  * W2[o * 192 + 64 + lane]
                       + uv  * W2[o * 192 + 128 + lane];
            part = waveReduceSum(part);
            float m2 = leakyf(part + b2[o]);
            acc3 = fmaf(m2, W3[o], acc3);
        }
        float w = rcp_(1.0f + __expf(-(acc3 + b3[0])));
        if (lane == 0) { uw[idx] = w; SfB[idx] = sf; p1B[idx] = pp; }
    }
}

// ---------------------------------------------------------------------------
// Fused tail kernel 2: preds (blocks 0..2047) + ssl (block 2048).
// ssl reads pergs outputs written by the previous kernel -> ordering OK.
// ---------------------------------------------------------------------------
__global__ __launch_bounds__(256)
void preds_ssl_kernel(const float* __restrict__ finalv, const float* __restrict__ att_user,
                      const int* __restrict__ uids, const int* __restrict__ iids,
                      const int* __restrict__ uLocs,
                      const float* __restrict__ uw, const float* __restrict__ SfB,
                      const float* __restrict__ p1B, float* __restrict__ out)
{
    const int lane = threadIdx.x & 63, wave = threadIdx.x >> 6;

    if (blockIdx.x < NPRED / 4) {
        const int n = blockIdx.x * 4 + wave;
        const int u = uids[n], it = iids[n], loc = uLocs[n];
        float fi = finalv[(size_t)(U_CNT + it) * D_DIM + lane];
        float fu = finalv[(size_t)u * D_DIM + lane];
        float au = leakyf(att_user[loc * D_DIM + lane]);
        float p = waveReduceSum(fu * fi + au * fi);
        if (lane == 0) out[n] = p;
    } else {
        // ---------------- ssl (single block, deterministic) ----------------
        const int tid = threadIdx.x;
        float local = 0.0f;
        for (int p = tid; p < G_CNT * 2048; p += 256) {
            int g = p >> 11, s = p & 2047;
            int ip = g * NS_CNT + s, in_ = ip + 2048;
            float Sf   = uw[ip] * SfB[ip] - uw[in_] * SfB[in_];
            float diff = p1B[ip] - p1B[in_];
            local += fmaxf(1.0f - Sf * diff, 0.0f);
        }
        local = waveReduceSum(local);
        __shared__ float part[4];
        if (lane == 0) part[wave] = local;
        __syncthreads();
        if (tid == 0) {
            float s = part[0] + part[1] + part[2] + part[3];
            out[NPRED] = s;
        }
    }
}

extern "C" void kernel_launch(void* const* d_in, const int* in_sizes, int n_in,
                              void* d_out, int out_size, void* d_ws, size_t ws_size,
                              hipStream_t stream)
{
    const float* uEmbed  = (const float*)d_in[0];
    const float* iEmbed  = (const float*)d_in[1];
    const float* posEmbed= (const float*)d_in[2];
    const float* Wih     = (const float*)d_in[3];
    const float* Whh     = (const float*)d_in[4];
    const float* bih     = (const float*)d_in[5];
    const float* bhh     = (const float*)d_in[6];
    const float* Wq0     = (const float*)d_in[7];
    const float* Wk0     = (const float*)d_in[8];
    const float* Wv0     = (const float*)d_in[9];
    const float* Wq1     = (const float*)d_in[10];
    const float* Wk1     = (const float*)d_in[11];
    const float* Wv1     = (const float*)d_in[12];
    const float* Wv_seq  = (const float*)d_in[15];
    const float* meta2_W = (const float*)d_in[16];
    const float* meta2_b = (const float*)d_in[17];
    const float* meta3_W = (const float*)d_in[18];
    const float* meta3_b = (const float*)d_in[19];
    const float* mask    = (const float*)d_in[20];
    const int*   uids    = (const int*)d_in[21];
    const int*   iids    = (const int*)d_in[22];
    const int*   sequence= (const int*)d_in[23];
    const int*   uLocs   = (const int*)d_in[24];
    const int*   suids   = (const int*)d_in[25];
    const int*   siids   = (const int*)d_in[26];

    char*  wsB      = (char*)d_ws;
    char*  fragtab  = wsB;                                 // 112KB frags
    float* biastab  = (float*)(wsB + 116 * 1024);          // 1KB bias
    float* finalv   = (float*)(wsB + 128 * 1024);          // N_ROWS*64
    float* att_user = finalv + (size_t)N_ROWS * D_DIM;     // B*64
    float* uwB      = att_user + (size_t)B_CNT * D_DIM;    // G*NS
    float* SfB      = uwB + (size_t)G_CNT * NS_CNT;
    float* p1B      = SfB + (size_t)G_CNT * NS_CNT;
    float* out      = (float*)d_out;

    prep_kernel<<<1, 512, 0, stream>>>(
        Wih, Whh, bih, bhh, Wq0, Wk0, Wv0, Wq1, Wk1, Wv1, fragtab, biastab);

    tower_kernel<<<(N_ROWS + 127) / 128, 512, 0, stream>>>(
        uEmbed, iEmbed, fragtab, biastab, finalv);

    seq_pergs_kernel<<<B_CNT / 4 + (G_CNT * NS_CNT) / 4, 256, 0, stream>>>(
        finalv, posEmbed, mask, sequence, Wv_seq, att_user,
        uEmbed, iEmbed, suids, siids, meta2_W, meta2_b, meta3_W, meta3_b,
        uwB, SfB, p1B);

    preds_ssl_kernel<<<NPRED / 4 + 1, 256, 0, stream>>>(
        finalv, att_user, uids, iids, uLocs, uwB, SfB, p1B, out);
}

// Round 23
// 189.390 us; speedup vs baseline: 1.3234x; 1.0011x over previous
//
#include <hip/hip_runtime.h>
#include <hip/hip_bf16.h>
#include <math.h>

#define G_CNT 4
#define U_CNT 100000
#define I_CNT 50000
#define N_ROWS (U_CNT + I_CNT)
#define D_DIM 64
#define T_STEPS 4
#define L_SEQ 50
#define B_CNT 2048
#define NPRED 8192
#define NS_CNT 4096
#define LEAKY_A 0.5f

typedef short bf16x8 __attribute__((ext_vector_type(8)));
typedef float f32x4 __attribute__((ext_vector_type(4)));

union U16B { unsigned u[4]; bf16x8 v; };

// f32x2 -> packed bf16x2 via HW v_cvt_pk_bf16_f32 (safe C++ path, no asm).
__device__ __forceinline__ unsigned pkbf(float a, float b) {
    __hip_bfloat162 t = __float22bfloat162_rn(float2{a, b});
    __hip_bfloat162_raw rw = t;             // POD: {unsigned short x, y}
    return (unsigned)rw.x | ((unsigned)rw.y << 16);
}
__device__ __forceinline__ float bf_lo(unsigned u) { return __uint_as_float(u << 16); }
__device__ __forceinline__ float bf_hi(unsigned u) { return __uint_as_float(u & 0xffff0000u); }

__device__ __forceinline__ float bcast(float v, int srcLane) {
    return __int_as_float(__builtin_amdgcn_readlane(__float_as_int(v), srcLane));
}

__device__ __forceinline__ float waveReduceSum(float v) {
    v += __shfl_xor(v, 1, 64);
    v += __shfl_xor(v, 2, 64);
    v += __shfl_xor(v, 4, 64);
    v += __shfl_xor(v, 8, 64);
    v += __shfl_xor(v, 16, 64);
    v += __shfl_xor(v, 32, 64);
    return v;
}

__device__ __forceinline__ float waveLayerNorm(float v) {
    float s  = waveReduceSum(v);
    float s2 = waveReduceSum(v * v);
    float mean = s * (1.0f / 64.0f);
    float var  = s2 * (1.0f / 64.0f) - mean * mean;
    return (v - mean) * rsqrtf(var + 1e-5f);
}

// r12 lesson: every f32 divide (no -ffast-math) = ~10-12 VALU instr.
__device__ __forceinline__ float rcp_(float x) { return __builtin_amdgcn_rcpf(x); }

__device__ __forceinline__ float sigm(float x) { return rcp_(1.0f + __expf(-x)); }
__device__ __forceinline__ float tanh_(float x) {
    float xc = fminf(x, 15.0f);
    float t = __expf(2.0f * xc);
    return (t - 1.0f) * rcp_(t + 1.0f);
}
__device__ __forceinline__ float leakyf(float x) { return x >= 0.0f ? x : LEAKY_A * x; }

// Gate-row permutation: lane (r,g)'s output dims == its own B-frag k-slots
// -> h/xn feed the next MFMA B operand as pure register reuse.
__device__ __forceinline__ int gate_perm(int m, int p) {
    int ty = m >> 2, mm = m & 3;
    return ty * 64 + 32 * (mm >> 1) + 8 * (p >> 2) + 4 * (mm & 1) + (p & 3);
}

// ---------------------------------------------------------------------------
// prep_kernel: one-shot pack of weight fragments into d_ws.
// Wih scaled by 3.0 (gates = (3Wih)@emb == Wih@(3emb)).
// ---------------------------------------------------------------------------
__global__ __launch_bounds__(512)
void prep_kernel(const float* __restrict__ Wih, const float* __restrict__ Whh,
                 const float* __restrict__ bih, const float* __restrict__ bhh,
                 const float* __restrict__ Wq0, const float* __restrict__ Wk0, const float* __restrict__ Wv0,
                 const float* __restrict__ Wq1, const float* __restrict__ Wk1, const float* __restrict__ Wv1,
                 char* __restrict__ fragtab, float* __restrict__ biastab)
{
    const int tid  = threadIdx.x;
    const int lane = tid & 63;
    const int wave = tid >> 6;
    const int r    = lane & 15;
    const int g    = lane >> 4;

#pragma unroll
    for (int i = 0; i < 8; ++i) {
        int f = wave * 8 + i;               // 0..63
        int m = f >> 2, kc = f & 3;
        int gate = gate_perm(m, r);
        int k0 = kc * 32 + 8 * g;
        const bool isX = (k0 < 64);
        const float sc = isX ? 3.0f : 1.0f;           // fold x3 into Wih
        const float* src = isX ? (Wih + gate * 64 + k0)
                               : (Whh + gate * 64 + (k0 - 64));
        float4 lo = *(const float4*)src;
        float4 hi = *(const float4*)(src + 4);
        U16B u;
        u.u[0] = pkbf(sc * lo.x, sc * lo.y); u.u[1] = pkbf(sc * lo.z, sc * lo.w);
        u.u[2] = pkbf(sc * hi.x, sc * hi.y); u.u[3] = pkbf(sc * hi.z, sc * hi.w);
        *(bf16x8*)(fragtab + f * 1024 + lane * 16) = u.v;
    }
#pragma unroll
    for (int i = 0; i < 6; ++i) {
        int f = 64 + i * 8 + wave;              // slot = wave = m*2+kc
        int m = (wave >> 1) & 3, kc = wave & 1;
        const float* WM = (i == 0) ? Wq0 : (i == 1) ? Wk0 : (i == 2) ? Wv0
                        : (i == 3) ? Wq1 : (i == 4) ? Wk1 : Wv1;
        int dp = m * 16 + r;
        int k0 = kc * 32 + 8 * g;
        float v0 = WM[(k0 + 0) * 64 + dp], v1 = WM[(k0 + 1) * 64 + dp];
        float v2 = WM[(k0 + 2) * 64 + dp], v3 = WM[(k0 + 3) * 64 + dp];
        float v4 = WM[(k0 + 4) * 64 + dp], v5 = WM[(k0 + 5) * 64 + dp];
        float v6 = WM[(k0 + 6) * 64 + dp], v7 = WM[(k0 + 7) * 64 + dp];
        U16B u;
        u.u[0] = pkbf(v0, v1); u.u[1] = pkbf(v2, v3);
        u.u[2] = pkbf(v4, v5); u.u[3] = pkbf(v6, v7);
        *(bf16x8*)(fragtab + f * 1024 + lane * 16) = u.v;
    }
    if (tid < 256) {
        int m = tid >> 4, p = tid & 15;
        int gate = gate_perm(m, p);
        biastab[tid] = bih[gate] + bhh[gate];
    }
}

// ---------------------------------------------------------------------------
// MFMA tower: 8 waves/block, 16 rows/wave; grid = ceil(N_ROWS/128) = 1172.
// Real t/head loops (r17: I$ fit). xnf in LDS during LSTM (r15: no spill);
// r22: hoisted back into REGISTERS for the QKV phase (read 8x instead of
// 32x -- drops 24 ds_read_b128 + lgkm waits from the head-loop critical
// path; QKV-phase peak ~120 regs < 128, WRITE_SIZE guards spill).
// C/D: col(lane&15)=row, M=4*(lane>>4)+reg [m89-verified].
// ---------------------------------------------------------------------------
__global__ __launch_bounds__(512)
void tower_kernel(const float* __restrict__ uEmbed, const float* __restrict__ iEmbed,
                  const char* __restrict__ fragtab, const float* __restrict__ biastab,
                  float* __restrict__ finalv)
{
    __shared__ char WFRAG[65536];   // LSTM frags 0..63, same layout as fragtab
    __shared__ char XNF[65536];     // per-wave 8KB: xnf[t][c][lane] bf16x8
    __shared__ float BSL[256];

    const int tid  = threadIdx.x;
    const int lane = tid & 63;
    const int wave = tid >> 6;
    const int r    = lane & 15;
    const int g    = lane >> 4;

    // ---- stage LSTM frags + bias into LDS (coalesced 16B/lane copies) ----
#pragma unroll
    for (int i = 0; i < 8; ++i) {
        int off = (wave * 8 + i) * 1024 + lane * 16;
        *(bf16x8*)(WFRAG + off) = *(const bf16x8*)(fragtab + off);
    }
    if (tid < 256) BSL[tid] = biastab[tid];
    __syncthreads();

    const int rowBase0 = blockIdx.x * 128 + wave * 16;
    const bool active  = rowBase0 < N_ROWS;            // wave-uniform (16 | N_ROWS)
    const int rowBase  = active ? rowBase0 : (N_ROWS - 16);
    const bool isUser = rowBase < U_CNT;               // 16 | 100000 -> wave-uniform
    const float* emb = isUser ? uEmbed : iEmbed;
    const int cnt = isUser ? U_CNT : I_CNT;
    const int rloc = (isUser ? rowBase : rowBase - U_CNT) + r;

    char* xnfw = XNF + wave * 8192;     // wave-private xnf stage

    float cst[4][4];
#pragma unroll
    for (int mm = 0; mm < 4; ++mm)
#pragma unroll
        for (int rg = 0; rg < 4; ++rg) cst[mm][rg] = 0.0f;

    uint2 hp4[4];                   // packed h of current step (perm'd dims)

#pragma unroll 1
    for (int t = 0; t < 4; ++t) {
        // ---- x B-frags for this step (raw emb; x3 folded into Wih) ----
        bf16x8 xft[2];
#pragma unroll
        for (int c = 0; c < 2; ++c) {
            const float* p = emb + ((size_t)t * cnt + rloc) * 64 + c * 32 + 8 * g;
            float4 lo = *(const float4*)p;
            float4 hi = *(const float4*)(p + 4);
            U16B u;
            u.u[0] = pkbf(lo.x, lo.y);
            u.u[1] = pkbf(lo.z, lo.w);
            u.u[2] = pkbf(hi.x, hi.y);
            u.u[3] = pkbf(hi.z, hi.w);
            xft[c] = u.v;
        }
        // ---- h B-frags: pure register reuse (gate_perm makes them lane-local)
        bf16x8 hfr[2];
        if (t > 0) {
#pragma unroll
            for (int c = 0; c < 2; ++c) {
                U16B u;
                u.u[0] = hp4[2 * c].x;     u.u[1] = hp4[2 * c].y;
                u.u[2] = hp4[2 * c + 1].x; u.u[3] = hp4[2 * c + 1].y;
                hfr[c] = u.v;
            }
        }
        __builtin_amdgcn_sched_barrier(0);       // B-frags settled

        // ---- per-mm gate groups; h kept in f32 (hvall) for LN ----
        float hvall[16];
#pragma unroll
        for (int mm = 0; mm < 4; ++mm) {
            f32x4 acc[4];               // ty = i,f,g,o ; gate tile m = ty*4+mm
#pragma unroll
            for (int ty = 0; ty < 4; ++ty)
                acc[ty] = *(const f32x4*)((const char*)BSL + (ty * 4 + mm) * 64 + g * 16);
#pragma unroll
            for (int kc = 0; kc < 2; ++kc)
#pragma unroll
                for (int ty = 0; ty < 4; ++ty) {
                    bf16x8 af = *(const bf16x8*)(WFRAG + ((ty * 4 + mm) * 4 + kc) * 1024 + lane * 16);
                    acc[ty] = __builtin_amdgcn_mfma_f32_16x16x32_bf16(af, xft[kc], acc[ty], 0, 0, 0);
                }
            if (t > 0) {
#pragma unroll
                for (int c = 0; c < 2; ++c)
#pragma unroll
                    for (int ty = 0; ty < 4; ++ty) {
                        bf16x8 af = *(const bf16x8*)(WFRAG + ((ty * 4 + mm) * 4 + 2 + c) * 1024 + lane * 16);
                        acc[ty] = __builtin_amdgcn_mfma_f32_16x16x32_bf16(af, hfr[c], acc[ty], 0, 0, 0);
                    }
            }
            // single-rcp cc: cc = [c(1+ei)(tg+1) + (tg-1)(1+ef)] * rcp((1+ef)(1+ei)(tg+1))
            // h = (tc-1) * rcp((1+eo)(tc+1))
#pragma unroll
            for (int rg = 0; rg < 4; ++rg) {
                float ei = __expf(-acc[0][rg]);
                float ef = __expf(-acc[1][rg]);
                float tg = __expf(2.0f * fminf(acc[2][rg], 15.0f));
                float eo = __expf(-acc[3][rg]);
                float a1 = 1.0f + ei, a2 = 1.0f + ef, a3 = tg + 1.0f, a4 = tg - 1.0f;
                float t13 = a1 * a3;
                float num = fmaf(cst[mm][rg], t13, a4 * a2);
                float cc  = num * rcp_(a2 * t13);
                cst[mm][rg] = cc;
                float tc = __expf(2.0f * fminf(cc, 15.0f));
                hvall[mm * 4 + rg] = (tc - 1.0f) * rcp_((1.0f + eo) * (tc + 1.0f));
            }
        }
        __builtin_amdgcn_sched_barrier(0);       // gate phase done

        // ---- LN on f32 h; pack hp4 (next-step h frags) + xn frags to LDS ----
        {
            float s = 0.f, s2 = 0.f;
#pragma unroll
            for (int i2 = 0; i2 < 16; ++i2) { s += hvall[i2]; s2 += hvall[i2] * hvall[i2]; }
            s  += __shfl_xor(s, 16, 64);  s  += __shfl_xor(s, 32, 64);
            s2 += __shfl_xor(s2, 16, 64); s2 += __shfl_xor(s2, 32, 64);
            float mean = s * (1.f / 64.f);
            float var  = s2 * (1.f / 64.f) - mean * mean;
            float rs = rsqrtf(var + 1e-5f);
            uint2 xp[4];
#pragma unroll
            for (int mm = 0; mm < 4; ++mm) {
                hp4[mm].x = pkbf(hvall[mm * 4 + 0], hvall[mm * 4 + 1]);
                hp4[mm].y = pkbf(hvall[mm * 4 + 2], hvall[mm * 4 + 3]);
                float x0 = (hvall[mm * 4 + 0] - mean) * rs, x1 = (hvall[mm * 4 + 1] - mean) * rs;
                float x2 = (hvall[mm * 4 + 2] - mean) * rs, x3 = (hvall[mm * 4 + 3] - mean) * rs;
                xp[mm].x = pkbf(x0, x1); xp[mm].y = pkbf(x2, x3);
            }
#pragma unroll
            for (int c = 0; c < 2; ++c) {
                U16B u;
                u.u[0] = xp[2 * c].x;     u.u[1] = xp[2 * c].y;
                u.u[2] = xp[2 * c + 1].x; u.u[3] = xp[2 * c + 1].y;
                *(bf16x8*)(xnfw + t * 2048 + c * 1024 + lane * 16) = u.v;
            }
        }
        __builtin_amdgcn_sched_barrier(0);       // pin t-iteration boundary
    }

    // ---- hoist xn frags back into registers (8 ds_reads, reused 4 heads) ----
    bf16x8 xnr[4][2];
#pragma unroll
    for (int t = 0; t < 4; ++t)
#pragma unroll
        for (int c = 0; c < 2; ++c)
            xnr[t][c] = *(const bf16x8*)(xnfw + t * 2048 + c * 1024 + lane * 16);

    // ---- per-head QKV + attention; REAL head loop (code size) ----
    const int base3 = isUser ? 0 : 3;
    float* dst = finalv + (size_t)(rowBase + r) * 64;

#pragma unroll 1
    for (int mm = 0; mm < 4; ++mm) {
        bf16x8 fq[2], fk[2], fv[2];
#pragma unroll
        for (int kc = 0; kc < 2; ++kc) {
            fq[kc] = *(const bf16x8*)(fragtab + (size_t)(64 + (0 + base3) * 8 + mm * 2 + kc) * 1024 + lane * 16);
            fk[kc] = *(const bf16x8*)(fragtab + (size_t)(64 + (1 + base3) * 8 + mm * 2 + kc) * 1024 + lane * 16);
            fv[kc] = *(const bf16x8*)(fragtab + (size_t)(64 + (2 + base3) * 8 + mm * 2 + kc) * 1024 + lane * 16);
        }
        float q[4][4], k[4][4], v[4][4];
#pragma unroll
        for (int t = 0; t < 4; ++t) {
            f32x4 aq = {0.f, 0.f, 0.f, 0.f};
            f32x4 ak = {0.f, 0.f, 0.f, 0.f};
            f32x4 av = {0.f, 0.f, 0.f, 0.f};
#pragma unroll
            for (int kc = 0; kc < 2; ++kc) {
                aq = __builtin_amdgcn_mfma_f32_16x16x32_bf16(fq[kc], xnr[t][kc], aq, 0, 0, 0);
                ak = __builtin_amdgcn_mfma_f32_16x16x32_bf16(fk[kc], xnr[t][kc], ak, 0, 0, 0);
                av = __builtin_amdgcn_mfma_f32_16x16x32_bf16(fv[kc], xnr[t][kc], av, 0, 0, 0);
            }
#pragma unroll
            for (int rg = 0; rg < 4; ++rg) {
                q[t][rg] = aq[rg]; k[t][rg] = ak[rg]; v[t][rg] = av[rg];
            }
        }
        float sc[4][4];                 // [t][s]
#pragma unroll
        for (int t = 0; t < 4; ++t)
#pragma unroll
            for (int s5 = 0; s5 < 4; ++s5) {
                float pr = q[t][0] * k[s5][0] + q[t][1] * k[s5][1]
                         + q[t][2] * k[s5][2] + q[t][3] * k[s5][3];
                pr += __shfl_xor(pr, 16, 64);
                pr += __shfl_xor(pr, 32, 64);
                sc[t][s5] = pr * 0.25f;
            }
        float o0 = 0.f, o1 = 0.f, o2 = 0.f, o3 = 0.f;
#pragma unroll
        for (int t = 0; t < 4; ++t) {
            float mx = fmaxf(fmaxf(sc[t][0], sc[t][1]), fmaxf(sc[t][2], sc[t][3]));
            float e0 = __expf(sc[t][0] - mx), e1 = __expf(sc[t][1] - mx);
            float e2 = __expf(sc[t][2] - mx), e3 = __expf(sc[t][3] - mx);
            float inv = rcp_(e0 + e1 + e2 + e3);
            float a0 = e0 * inv, a1 = e1 * inv, a2 = e2 * inv, a3 = e3 * inv;
            o0 += a0 * v[0][0] + a1 * v[1][0] + a2 * v[2][0] + a3 * v[3][0];
            o1 += a0 * v[0][1] + a1 * v[1][1] + a2 * v[2][1] + a3 * v[3][1];
            o2 += a0 * v[0][2] + a1 * v[1][2] + a2 * v[2][2] + a3 * v[3][2];
            o3 += a0 * v[0][3] + a1 * v[1][3] + a2 * v[2][3] + a3 * v[3][3];
        }
        if (active) {
            float4 o4 = { o0 * 0.25f, o1 * 0.25f, o2 * 0.25f, o3 * 0.25f };
            *(float4*)(dst + mm * 16 + 4 * g) = o4;
        }
    }
}

// ---------------------------------------------------------------------------
// Fused tail kernel 1: seq_att (blocks 0..511) + pergs (blocks 512..4607).
// Both depend only on finalv -> safe in one launch.
// ---------------------------------------------------------------------------
__global__ __launch_bounds__(256)
void seq_pergs_kernel(const float* __restrict__ finalv, const float* __restrict__ posEmbed,
                      const float* __restrict__ mask, const int* __restrict__ sequence,
                      const float* __restrict__ Wv_seq, float* __restrict__ att_user,
                      const float* __restrict__ uEmbed, const float* __restrict__ iEmbed,
                      const int* __restrict__ suids, const int* __restrict__ siids,
                      const float* __restrict__ W2, const float* __restrict__ b2,
                      const float* __restrict__ W3, const float* __restrict__ b3,
                      float* __restrict__ uw, float* __restrict__ SfB, float* __restrict__ p1B)
{
    const int lane = threadIdx.x & 63, wave = threadIdx.x >> 6;

    if (blockIdx.x < B_CNT / 4) {
        // ---------------- seq_att ----------------
        const int b = blockIdx.x * 4 + wave;
        const float* fitem = finalv + (size_t)U_CNT * D_DIM;

        float acc = 0.0f;
        for (int l = 0; l < L_SEQ; ++l) {
            int   sid = sequence[b * L_SEQ + l];
            float m   = mask[b * L_SEQ + l];
            acc += m * (fitem[(size_t)sid * D_DIM + lane] + posEmbed[l * D_DIM + lane]);
        }
        float att = waveLayerNorm(acc);   // sb
#pragma unroll
        for (int layer = 0; layer < 2; ++layer) {
            float xnv = waveLayerNorm(att);
            float vv = 0.0f;
            const float* Wv = Wv_seq + layer * 64 * 64;
            for (int j = 0; j < 64; ++j)
                vv = fmaf(bcast(xnv, j), Wv[j * 64 + lane], vv);
            att = leakyf(vv) + att;
        }
        att_user[b * D_DIM + lane] = att;
    } else {
        // ---------------- pergs ----------------
        const int idx = (blockIdx.x - B_CNT / 4) * 4 + wave;   // 0 .. G*NS-1
        const int g  = idx >> 12;                              // NS_CNT == 4096
        const int su = suids[idx], si = siids[idx];

        float fu = finalv[(size_t)su * D_DIM + lane];
        float fi = finalv[(size_t)(U_CNT + si) * D_DIM + lane];
        float uv = 3.0f * uEmbed[((size_t)g * U_CNT + su) * D_DIM + lane];
        float iv = 3.0f * iEmbed[((size_t)g * I_CNT + si) * D_DIM + lane];

        float sf = waveReduceSum(leakyf(fu * fi));
        float pp = waveReduceSum(leakyf(uv * iv));

        float m1a = fu * uv;
        float acc3 = 0.0f;
        for (int o = 0; o < 32; ++o) {
            float part = m1a * W2[o * 192 + lane]
                       + fu  * W2[o * 192 + 64 + lane]
                       + uv  * W2[o * 192 + 128 + lane];
            part = waveReduceSum(part);
            float m2 = leakyf(part + b2[o]);
            acc3 = fmaf(m2, W3[o], acc3);
        }
        float w = rcp_(1.0f + __expf(-(acc3 + b3[0])));
        if (lane == 0) { uw[idx] = w; SfB[idx] = sf; p1B[idx] = pp; }
    }
}

// ---------------------------------------------------------------------------
// Fused tail kernel 2: preds (blocks 0..2047) + ssl (block 2048).
// ssl reads pergs outputs written by the previous kernel -> ordering OK.
// ---------------------------------------------------------------------------
__global__ __launch_bounds__(256)
void preds_ssl_kernel(const float* __restrict__ finalv, const float* __restrict__ att_user,
                      const int* __restrict__ uids, const int* __restrict__ iids,
                      const int* __restrict__ uLocs,
                      const float* __restrict__ uw, const float* __restrict__ SfB,
                      const float* __restrict__ p1B, float* __restrict__ out)
{
    const int lane = threadIdx.x & 63, wave = threadIdx.x >> 6;

    if (blockIdx.x < NPRED / 4) {
        const int n = blockIdx.x * 4 + wave;
        const int u = uids[n], it = iids[n], loc = uLocs[n];
        float fi = finalv[(size_t)(U_CNT + it) * D_DIM + lane];
        float fu = finalv[(size_t)u * D_DIM + lane];
        float au = leakyf(att_user[loc * D_DIM + lane]);
        float p = waveReduceSum(fu * fi + au * fi);
        if (lane == 0) out[n] = p;
    } else {
        // ---------------- ssl (single block, deterministic) ----------------
        const int tid = threadIdx.x;
        float local = 0.0f;
        for (int p = tid; p < G_CNT * 2048; p += 256) {
            int g = p >> 11, s = p & 2047;
            int ip = g * NS_CNT + s, in_ = ip + 2048;
            float Sf   = uw[ip] * SfB[ip] - uw[in_] * SfB[in_];
            float diff = p1B[ip] - p1B[in_];
            local += fmaxf(1.0f - Sf * diff, 0.0f);
        }
        local = waveReduceSum(local);
        __shared__ float part[4];
        if (lane == 0) part[wave] = local;
        __syncthreads();
        if (tid == 0) {
            float s = part[0] + part[1] + part[2] + part[3];
            out[NPRED] = s;
        }
    }
}

extern "C" void kernel_launch(void* const* d_in, const int* in_sizes, int n_in,
                              void* d_out, int out_size, void* d_ws, size_t ws_size,
                              hipStream_t stream)
{
    const float* uEmbed  = (const float*)d_in[0];
    const float* iEmbed  = (const float*)d_in[1];
    const float* posEmbed= (const float*)d_in[2];
    const float* Wih     = (const float*)d_in[3];
    const float* Whh     = (const float*)d_in[4];
    const float* bih     = (const float*)d_in[5];
    const float* bhh     = (const float*)d_in[6];
    const float* Wq0     = (const float*)d_in[7];
    const float* Wk0     = (const float*)d_in[8];
    const float* Wv0     = (const float*)d_in[9];
    const float* Wq1     = (const float*)d_in[10];
    const float* Wk1     = (const float*)d_in[11];
    const float* Wv1     = (const float*)d_in[12];
    const float* Wv_seq  = (const float*)d_in[15];
    const float* meta2_W = (const float*)d_in[16];
    const float* meta2_b = (const float*)d_in[17];
    const float* meta3_W = (const float*)d_in[18];
    const float* meta3_b = (const float*)d_in[19];
    const float* mask    = (const float*)d_in[20];
    const int*   uids    = (const int*)d_in[21];
    const int*   iids    = (const int*)d_in[22];
    const int*   sequence= (const int*)d_in[23];
    const int*   uLocs   = (const int*)d_in[24];
    const int*   suids   = (const int*)d_in[25];
    const int*   siids   = (const int*)d_in[26];

    char*  wsB      = (char*)d_ws;
    char*  fragtab  = wsB;                                 // 112KB frags
    float* biastab  = (float*)(wsB + 116 * 1024);          // 1KB bias
    float* finalv   = (float*)(wsB + 128 * 1024);          // N_ROWS*64
    float* att_user = finalv + (size_t)N_ROWS * D_DIM;     // B*64
    float* uwB      = att_user + (size_t)B_CNT * D_DIM;    // G*NS
    float* SfB      = uwB + (size_t)G_CNT * NS_CNT;
    float* p1B      = SfB + (size_t)G_CNT * NS_CNT;
    float* out      = (float*)d_out;

    prep_kernel<<<1, 512, 0, stream>>>(
        Wih, Whh, bih, bhh, Wq0, Wk0, Wv0, Wq1, Wk1, Wv1, fragtab, biastab);

    tower_kernel<<<(N_ROWS + 127) / 128, 512, 0, stream>>>(
        uEmbed, iEmbed, fragtab, biastab, finalv);

    seq_pergs_kernel<<<B_CNT / 4 + (G_CNT * NS_CNT) / 4, 256, 0, stream>>>(
        finalv, posEmbed, mask, sequence, Wv_seq, att_user,
        uEmbed, iEmbed, suids, siids, meta2_W, meta2_b, meta3_W, meta3_b,
        uwB, SfB, p1B);

    preds_ssl_kernel<<<NPRED / 4 + 1, 256, 0, stream>>>(
        finalv, att_user, uids, iids, uLocs, uwB, SfB, p1B, out);
}